// Round 4
// baseline (844.883 us; speedup 1.0000x reference)
//
#include <hip/hip_runtime.h>
#include <hip/hip_cooperative_groups.h>
#include <math.h>
#include <stdint.h>

#define D 128
#define EPS 1e-6f
typedef unsigned short u16;

namespace cg = cooperative_groups;

// ---------------------------------------------------------------------------
// state layout (floats), 16B-aligned base:
//   st[0..127]   : q
//   st[128..255] : q_plus
//   st[256..383] : hop accumulator (numerator of weighted value sum)
//   st[384]      : ||q||
//   st[385]      : ||q_plus||
//   st[386]      : sum of exp (softmax denominator accumulator)
// ---------------------------------------------------------------------------

__device__ __forceinline__ float wave_sum(float v) {
#pragma unroll
    for (int off = 32; off > 0; off >>= 1) v += __shfl_xor(v, off, 64);
    return v;
}
__device__ __forceinline__ float halfwave_sum(float v) {
#pragma unroll
    for (int off = 16; off > 0; off >>= 1) v += __shfl_xor(v, off, 32);
    return v;
}

__device__ __forceinline__ float bf2f(u16 h) {
    union { unsigned u; float f; } x;
    x.u = ((unsigned)h) << 16;
    return x.f;
}
__device__ __forceinline__ u16 f2bf(float f) {  // round-to-nearest-even
    union { float f; unsigned u; } x;
    x.f = f;
    unsigned u = x.u;
    return (u16)((u + 0x7fff + ((u >> 16) & 1)) >> 16);
}

// ===========================================================================
// Block-level (256-thread) hop bodies. Threads 128..255 participate only in
// __syncthreads. All __shfl regions are guarded to full waves 0-1.
// ===========================================================================

__device__ void persona_hop_body(const float* __restrict__ pers_rows,
                                 const float* __restrict__ pnorms,
                                 const float* __restrict__ W,
                                 float* __restrict__ st, int NP) {
    __shared__ float qsh[D];
    __shared__ float att[64];
    __shared__ float qh[D];
    __shared__ float red[2];
    int tid = threadIdx.x;
    if (tid < D) qsh[tid] = st[tid];
    __syncthreads();
    if (tid < NP) {
        float dot = 0.f;
        for (int d2 = 0; d2 < D; ++d2) dot += pers_rows[tid * D + d2] * qsh[d2];
        att[tid] = dot / fmaxf(pnorms[tid] * st[384], EPS);
    }
    __syncthreads();
    if (tid == 0) {
        float m = -1e30f;
        for (int p = 0; p < NP; ++p) m = fmaxf(m, att[p]);
        float s = 0.f;
        for (int p = 0; p < NP; ++p) { att[p] = __expf(att[p] - m); s += att[p]; }
        float inv = 1.f / s;
        for (int p = 0; p < NP; ++p) att[p] *= inv;
    }
    __syncthreads();
    if (tid < D) {
        float h = 0.f;
        for (int p = 0; p < NP; ++p) h += att[p] * pers_rows[p * D + tid];
        qh[tid] = qsh[tid] + h;
    }
    __syncthreads();
    if (tid < D) {
        float qp = 0.f;
        for (int d2 = 0; d2 < D; ++d2) qp += W[tid * D + d2] * qh[d2];
        st[128 + tid] = qp;
        float sq = wave_sum(qp * qp);
        if ((tid & 63) == 0) red[tid >> 6] = sq;
    }
    __syncthreads();
    if (tid == 0) st[385] = sqrtf(red[0] + red[1]);
    if (tid < 128) st[256 + tid] = 0.f;
    if (tid == 0) st[386] = 0.f;
}

__device__ void mid_hop_body(const float* __restrict__ W1,
                             const float* __restrict__ W2,
                             const float* __restrict__ pers_rows,
                             const float* __restrict__ pnorms,
                             float* __restrict__ st, int NP) {
    __shared__ float qh[D];
    __shared__ float qsh[D];
    __shared__ float att[64];
    __shared__ float red[2];
    int tid = threadIdx.x;
    if (tid < D) {
        float inv = 1.f / st[386];
        qh[tid] = st[128 + tid] + st[256 + tid] * inv;
    }
    __syncthreads();
    if (tid < D) {
        float qn = 0.f;
        for (int d2 = 0; d2 < D; ++d2) qn += W1[tid * D + d2] * qh[d2];
        qsh[tid] = qn;
        st[tid] = qn;
        float sq = wave_sum(qn * qn);
        if ((tid & 63) == 0) red[tid >> 6] = sq;
    }
    __syncthreads();
    float qnorm = sqrtf(red[0] + red[1]);
    if (tid == 0) st[384] = qnorm;
    if (tid < NP) {
        float dot = 0.f;
        for (int d2 = 0; d2 < D; ++d2) dot += pers_rows[tid * D + d2] * qsh[d2];
        att[tid] = dot / fmaxf(pnorms[tid] * qnorm, EPS);
    }
    __syncthreads();
    if (tid == 0) {
        float m = -1e30f;
        for (int p = 0; p < NP; ++p) m = fmaxf(m, att[p]);
        float s = 0.f;
        for (int p = 0; p < NP; ++p) { att[p] = __expf(att[p] - m); s += att[p]; }
        float is = 1.f / s;
        for (int p = 0; p < NP; ++p) att[p] *= is;
    }
    __syncthreads();
    if (tid < D) {
        float h = 0.f;
        for (int p = 0; p < NP; ++p) h += att[p] * pers_rows[p * D + tid];
        qh[tid] = qsh[tid] + h;
    }
    __syncthreads();
    if (tid < D) {
        float qp = 0.f;
        for (int d2 = 0; d2 < D; ++d2) qp += W2[tid * D + d2] * qh[d2];
        st[128 + tid] = qp;
        float sq2 = wave_sum(qp * qp);
        if ((tid & 63) == 0) red[tid >> 6] = sq2;
    }
    __syncthreads();
    if (tid == 0) st[385] = sqrtf(red[0] + red[1]);
    if (tid < 128) st[256 + tid] = 0.f;
    if (tid == 0) st[386] = 0.f;
}

__device__ void finish_hop_body(const float* __restrict__ W,
                                float* __restrict__ st) {
    __shared__ float qh[D];
    __shared__ float red[2];
    int tid = threadIdx.x;
    if (tid < D) {
        float inv = 1.f / st[386];
        qh[tid] = st[128 + tid] + st[256 + tid] * inv;
    }
    __syncthreads();
    if (tid < D) {
        float qn = 0.f;
        for (int d2 = 0; d2 < D; ++d2) qn += W[tid * D + d2] * qh[d2];
        st[tid] = qn;
        float sq = wave_sum(qn * qn);
        if ((tid & 63) == 0) red[tid >> 6] = sq;
    }
    __syncthreads();
    if (tid == 0) st[384] = sqrtf(red[0] + red[1]);
}

// Fused big attention over bf16 rows (grid-strided over row pairs).
__device__ void big_att_body(const u16* __restrict__ krows,
                             const float* __restrict__ knorms,
                             const u16* __restrict__ vrows,
                             float* __restrict__ st, int N, int gw, int nw) {
    __shared__ float s[129];
    int tid = threadIdx.x;
    int lane = tid & 63;
    int half = lane >> 5, hl = lane & 31;
    const float4 qp = *(const float4*)(st + 128 + 4 * hl);
    const float qpn = st[385];
    float4 acc = {0.f, 0.f, 0.f, 0.f};
    float esum = 0.f;
    const int npair = N >> 1;
    for (int p = gw; p < npair; p += nw) {
        const int i = 2 * p + half;
        const ushort4 kh = *(const ushort4*)(krows + (long)i * D + 4 * hl);
        float dot = bf2f(kh.x) * qp.x + bf2f(kh.y) * qp.y +
                    bf2f(kh.z) * qp.z + bf2f(kh.w) * qp.w;
        dot = halfwave_sum(dot);
        const float c = dot / fmaxf(knorms[i] * qpn, EPS);
        const float e = __expf(c);
        const ushort4 vh = *(const ushort4*)(vrows + (long)i * D + 4 * hl);
        acc.x += e * bf2f(vh.x);
        acc.y += e * bf2f(vh.y);
        acc.z += e * bf2f(vh.z);
        acc.w += e * bf2f(vh.w);
        if (hl == 0) esum += e;
    }
    acc.x += __shfl_xor(acc.x, 32, 64);
    acc.y += __shfl_xor(acc.y, 32, 64);
    acc.z += __shfl_xor(acc.z, 32, 64);
    acc.w += __shfl_xor(acc.w, 32, 64);
    esum += __shfl_xor(esum, 32, 64);
    if (tid < 129) s[tid] = 0.f;
    __syncthreads();
    if (half == 0) {
        atomicAdd(&s[4 * hl + 0], acc.x);
        atomicAdd(&s[4 * hl + 1], acc.y);
        atomicAdd(&s[4 * hl + 2], acc.z);
        atomicAdd(&s[4 * hl + 3], acc.w);
        if (hl == 0) atomicAdd(&s[128], esum);
    }
    __syncthreads();
    if (tid < 128) atomicAdd(&st[256 + tid], s[tid]);
    if (tid == 128) atomicAdd(&st[386], s[128]);
}

// ===========================================================================
// The single cooperative kernel.
// ===========================================================================
struct FusedArgs {
    const int* xs;
    const int* cands;
    const int* pers;
    const int* keys;
    const int* values;
    const float* semb;
    const float* cemb;
    const float* RW;
    const float* R2W;
    float* out;
    u16* tbl16;
    u16* kb;
    u16* vb;
    float* knorms;
    float* enc_cands;
    float* cnorms;
    float* enc_pers;
    float* pnorms;
    float* st;
    int n4;     // VD/4
    int NMEM;
    int NCAND;
    int NPERS;
    int LQ;
};

__global__ __launch_bounds__(256, 4) void fused_all(FusedArgs a) {
    cg::grid_group grid = cg::this_grid();
    const int tid = threadIdx.x;
    const int bid = blockIdx.x;
    const int nb = gridDim.x;
    const int gthreads = nb * 256;
    const int gtid = bid * 256 + tid;
    const int lane = tid & 63;
    const int half = lane >> 5;
    const int hl = lane & 31;
    const int gw = gtid >> 6;      // global wave id
    const int nw = gthreads >> 6;  // global wave count

    // ---- Phase A1: fp32 -> bf16 table convert (all blocks, streaming) ----
    {
        const float4* src = (const float4*)a.semb;
        ushort4* dst = (ushort4*)a.tbl16;
        for (int i = gtid; i < a.n4; i += gthreads) {
            float4 v = src[i];
            ushort4 o;
            o.x = f2bf(v.x); o.y = f2bf(v.y); o.z = f2bf(v.z); o.w = f2bf(v.w);
            dst[i] = o;
        }
    }

    // ---- Phase A2: candidate encode, fp32 pair scheme (all blocks) ----
    {
        const int npair = (a.NCAND + 1) >> 1;
        for (int p = gw; p < npair; p += nw) {
            const int row = 2 * p + half;
            const bool valid = row < a.NCAND;
            const int rowc = valid ? row : (a.NCAND - 1);
            int myid = 0;
            if (hl < 20) myid = a.cands[(long)rowc * 20 + hl];
            float4 acc = {0.f, 0.f, 0.f, 0.f};
#pragma unroll
            for (int t = 0; t < 20; ++t) {
                const int idx = __shfl(myid, (half << 5) + t, 64);
                const float4 e = *(const float4*)(a.cemb + (long)idx * D + 4 * hl);
                acc.x += e.x; acc.y += e.y; acc.z += e.z; acc.w += e.w;
            }
            if (valid) {
                *(float4*)(a.enc_cands + (long)row * D + 4 * hl) = acc;
                float sq = acc.x * acc.x + acc.y * acc.y + acc.z * acc.z + acc.w * acc.w;
                sq = halfwave_sum(sq);
                if (hl == 0) a.cnorms[row] = sqrtf(sq);
            }
        }
    }

    // ---- Phase A3: persona rows + q (block 0 only; virtual row NPERS = q) --
    if (bid == 0) {
        const int npr = a.NPERS + 1;
        const int npairs = (npr + 1) >> 1;
        const int bw = tid >> 6;
        for (int p = bw; p < npairs; p += 4) {
            const int row = 2 * p + half;
            const bool valid = row < npr;
            const int rowc = valid ? row : 0;
            const bool isq = (rowc == a.NPERS);
            const int* ids = isq ? a.xs : (a.pers + (long)rowc * 20);
            const int L = isq ? a.LQ : 20;
            int myid = 0;
            if (hl < L) myid = ids[hl];
            float4 acc = {0.f, 0.f, 0.f, 0.f};
            for (int t = 0; t < L; ++t) {
                const int idx = __shfl(myid, (half << 5) + t, 64);
                const float4 e = *(const float4*)(a.semb + (long)idx * D + 4 * hl);
                acc.x += e.x; acc.y += e.y; acc.z += e.z; acc.w += e.w;
            }
            if (valid) {
                float* outp = isq ? a.st : (a.enc_pers + (long)rowc * D);
                *(float4*)(outp + 4 * hl) = acc;
                float sq = acc.x * acc.x + acc.y * acc.y + acc.z * acc.z + acc.w * acc.w;
                sq = halfwave_sum(sq);
                if (hl == 0) {
                    if (isq) a.st[384] = sqrtf(sq);
                    else a.pnorms[rowc] = sqrtf(sq);
                }
            }
        }
    }
    __threadfence();
    grid.sync();

    // ---- Phase B: kv encode (blocks 1..nb-1) || persona hop 1 (block 0) ----
    if (bid == 0) {
        persona_hop_body(a.enc_pers, a.pnorms, a.RW, a.st, a.NPERS);
    } else {
        const int gw2 = (bid - 1) * 4 + (tid >> 6);
        const int nw2 = (nb - 1) * 4;
        const int npair = a.NMEM >> 1;  // NMEM even
        for (int p = gw2; p < npair; p += nw2) {
            const int row = 2 * p + half;
            int kid = 0, vid = 0;
            if (hl < 20) {
                kid = a.keys[(long)row * 20 + hl];
                vid = a.values[(long)row * 20 + hl];
            }
            float4 ka = {0.f, 0.f, 0.f, 0.f}, va = {0.f, 0.f, 0.f, 0.f};
#pragma unroll
            for (int t = 0; t < 20; ++t) {
                const int ki = __shfl(kid, (half << 5) + t, 64);
                const int vi = __shfl(vid, (half << 5) + t, 64);
                const ushort4 ke = *(const ushort4*)(a.tbl16 + (long)ki * D + 4 * hl);
                const ushort4 ve = *(const ushort4*)(a.tbl16 + (long)vi * D + 4 * hl);
                ka.x += bf2f(ke.x); ka.y += bf2f(ke.y);
                ka.z += bf2f(ke.z); ka.w += bf2f(ke.w);
                va.x += bf2f(ve.x); va.y += bf2f(ve.y);
                va.z += bf2f(ve.z); va.w += bf2f(ve.w);
            }
            ushort4 ko, vo;
            ko.x = f2bf(ka.x); ko.y = f2bf(ka.y); ko.z = f2bf(ka.z); ko.w = f2bf(ka.w);
            vo.x = f2bf(va.x); vo.y = f2bf(va.y); vo.z = f2bf(va.z); vo.w = f2bf(va.w);
            *(ushort4*)(a.kb + (long)row * D + 4 * hl) = ko;
            *(ushort4*)(a.vb + (long)row * D + 4 * hl) = vo;
            float sq = ka.x * ka.x + ka.y * ka.y + ka.z * ka.z + ka.w * ka.w;
            sq = halfwave_sum(sq);
            if (hl == 0) a.knorms[row] = sqrtf(sq);
        }
    }
    __threadfence();
    grid.sync();

    // ---- Phase C: big attention, hop 1 ----
    big_att_body(a.kb, a.knorms, a.vb, a.st, a.NMEM, gw, nw);
    __threadfence();
    grid.sync();

    // ---- Phase D: finish hop 1 + persona hop 2 (block 0) ----
    if (bid == 0) mid_hop_body(a.RW, a.R2W, a.enc_pers, a.pnorms, a.st, a.NPERS);
    __threadfence();
    grid.sync();

    // ---- Phase E: big attention, hop 2 ----
    big_att_body(a.kb, a.knorms, a.vb, a.st, a.NMEM, gw, nw);
    __threadfence();
    grid.sync();

    // ---- Phase F: finish hop 2 (block 0) ----
    if (bid == 0) finish_hop_body(a.R2W, a.st);
    __threadfence();
    grid.sync();

    // ---- Phase G: final candidate cosine (one wave per row) ----
    {
        const float2 q = *(const float2*)(a.st + 2 * lane);
        const float qn = a.st[384];
        for (int i = gw; i < a.NCAND; i += nw) {
            const float2 c = *(const float2*)(a.enc_cands + (long)i * D + 2 * lane);
            float dot = wave_sum(c.x * q.x + c.y * q.y);
            if (lane == 0) a.out[i] = dot / fmaxf(a.cnorms[i] * qn, EPS);
        }
    }
}

// ===========================================================================
// Fallback multi-kernel path (round-3 kernels, known-good).
// ===========================================================================

__global__ void table_to_bf16(const float4* __restrict__ src,
                              ushort4* __restrict__ dst, int n4) {
    int i = blockIdx.x * blockDim.x + threadIdx.x;
    if (i < n4) {
        float4 v = src[i];
        ushort4 o;
        o.x = f2bf(v.x); o.y = f2bf(v.y); o.z = f2bf(v.z); o.w = f2bf(v.w);
        dst[i] = o;
    }
}

template <int L>
__global__ void encode_kv_bf16(const u16* __restrict__ tbl,
                               const int* __restrict__ kids,
                               const int* __restrict__ vids, int N,
                               u16* __restrict__ krows, u16* __restrict__ vrows,
                               float* __restrict__ knorms) {
    const int lane = threadIdx.x & 63;
    const int half = lane >> 5;
    const int hl = lane & 31;
    int gw = (int)((blockIdx.x * blockDim.x + threadIdx.x) >> 6);
    int nw = (int)((gridDim.x * blockDim.x) >> 6);
    const int npair = (N + 1) >> 1;
    for (int p = gw; p < npair; p += nw) {
        const int row = 2 * p + half;
        const bool valid = row < N;
        const int rowc = valid ? row : (N - 1);
        int kid = 0, vid = 0;
        if (hl < L) {
            kid = kids[(long)rowc * L + hl];
            vid = vids[(long)rowc * L + hl];
        }
        float4 ka = {0.f, 0.f, 0.f, 0.f}, va = {0.f, 0.f, 0.f, 0.f};
#pragma unroll
        for (int t = 0; t < L; ++t) {
            const int ki = __shfl(kid, (half << 5) + t, 64);
            const int vi = __shfl(vid, (half << 5) + t, 64);
            const ushort4 ke = *(const ushort4*)(tbl + (long)ki * D + 4 * hl);
            const ushort4 ve = *(const ushort4*)(tbl + (long)vi * D + 4 * hl);
            ka.x += bf2f(ke.x); ka.y += bf2f(ke.y);
            ka.z += bf2f(ke.z); ka.w += bf2f(ke.w);
            va.x += bf2f(ve.x); va.y += bf2f(ve.y);
            va.z += bf2f(ve.z); va.w += bf2f(ve.w);
        }
        if (valid) {
            ushort4 ko, vo;
            ko.x = f2bf(ka.x); ko.y = f2bf(ka.y); ko.z = f2bf(ka.z); ko.w = f2bf(ka.w);
            vo.x = f2bf(va.x); vo.y = f2bf(va.y); vo.z = f2bf(va.z); vo.w = f2bf(va.w);
            *(ushort4*)(krows + (long)row * D + 4 * hl) = ko;
            *(ushort4*)(vrows + (long)row * D + 4 * hl) = vo;
        }
        float sq = ka.x * ka.x + ka.y * ka.y + ka.z * ka.z + ka.w * ka.w;
        sq = halfwave_sum(sq);
        if (valid && hl == 0) knorms[row] = sqrtf(sq);
    }
}

template <int L>
__global__ void encode_pairs(const float* __restrict__ table,
                             const int* __restrict__ ids, int N,
                             float* __restrict__ rows_out,
                             float* __restrict__ norms_out) {
    const int lane = threadIdx.x & 63;
    const int half = lane >> 5;
    const int hl = lane & 31;
    int gw = (int)((blockIdx.x * blockDim.x + threadIdx.x) >> 6);
    int nw = (int)((gridDim.x * blockDim.x) >> 6);
    const int npair = (N + 1) >> 1;
    for (int p = gw; p < npair; p += nw) {
        const int row = 2 * p + half;
        const bool valid = row < N;
        const int rowc = valid ? row : (N - 1);
        int myid = 0;
        if (hl < L) myid = ids[(long)rowc * L + hl];
        float4 acc = {0.f, 0.f, 0.f, 0.f};
#pragma unroll
        for (int t = 0; t < L; ++t) {
            const int idx = __shfl(myid, (half << 5) + t, 64);
            const float4 e = *(const float4*)(table + (long)idx * D + 4 * hl);
            acc.x += e.x; acc.y += e.y; acc.z += e.z; acc.w += e.w;
        }
        if (valid) *(float4*)(rows_out + (long)row * D + 4 * hl) = acc;
        float sq = acc.x * acc.x + acc.y * acc.y + acc.z * acc.z + acc.w * acc.w;
        sq = halfwave_sum(sq);
        if (valid && hl == 0) norms_out[row] = sqrtf(sq);
    }
}

__global__ void encode_small(const float* __restrict__ emb,
                             const int* __restrict__ pers, int NP, int LP,
                             const int* __restrict__ xs, int LQ,
                             float* __restrict__ pers_rows,
                             float* __restrict__ pnorms,
                             float* __restrict__ st) {
    int lane = threadIdx.x & 63;
    int w = threadIdx.x >> 6;
    for (int i = w; i <= NP; i += 4) {
        const int* ids;
        int L;
        float* out;
        float* nrm;
        if (i < NP) { ids = pers + (long)i * LP; L = LP; out = pers_rows + (long)i * D; nrm = pnorms + i; }
        else        { ids = xs; L = LQ; out = st; nrm = st + 384; }
        float2 acc = {0.f, 0.f};
        for (int t = 0; t < L; ++t) {
            int idx = ids[t];
            const float2 e = *(const float2*)(emb + (long)idx * D + 2 * lane);
            acc.x += e.x;
            acc.y += e.y;
        }
        *(float2*)(out + 2 * lane) = acc;
        float sq = wave_sum(acc.x * acc.x + acc.y * acc.y);
        if (lane == 0) *nrm = sqrtf(sq);
    }
}

__global__ void persona_hop_k(const float* __restrict__ pers_rows,
                              const float* __restrict__ pnorms,
                              const float* __restrict__ W,
                              float* __restrict__ st, int NP) {
    persona_hop_body(pers_rows, pnorms, W, st, NP);
}

__global__ void big_att_bf16_k(const u16* __restrict__ krows,
                               const float* __restrict__ knorms,
                               const u16* __restrict__ vrows,
                               float* __restrict__ st, int N) {
    int gw = (int)((blockIdx.x * blockDim.x + threadIdx.x) >> 6);
    int nw = (int)((gridDim.x * blockDim.x) >> 6);
    big_att_body(krows, knorms, vrows, st, N, gw, nw);
}

__global__ void big_att_rc(const float* __restrict__ emb,
                           const int* __restrict__ kids,
                           const int* __restrict__ vids,
                           float* __restrict__ st, int N, int L) {
    __shared__ float s[129];
    int tid = threadIdx.x;
    int lane = tid & 63;
    int gw = (int)((blockIdx.x * blockDim.x + tid) >> 6);
    int nw = (int)((gridDim.x * blockDim.x) >> 6);
    float2 qp = *(const float2*)(st + 128 + 2 * lane);
    float qpn = st[385];
    float2 acc = {0.f, 0.f};
    float esum = 0.f;
    for (int i = gw; i < N; i += nw) {
        float2 k = {0.f, 0.f};
        const int* kr = kids + (long)i * L;
        for (int t = 0; t < L; ++t) {
            const float2 e = *(const float2*)(emb + (long)kr[t] * D + 2 * lane);
            k.x += e.x;
            k.y += e.y;
        }
        float nsq = wave_sum(k.x * k.x + k.y * k.y);
        float dot = wave_sum(k.x * qp.x + k.y * qp.y);
        float c = dot / fmaxf(sqrtf(nsq) * qpn, EPS);
        float e = __expf(c);
        float2 v = {0.f, 0.f};
        const int* vr = vids + (long)i * L;
        for (int t = 0; t < L; ++t) {
            const float2 ev = *(const float2*)(emb + (long)vr[t] * D + 2 * lane);
            v.x += ev.x;
            v.y += ev.y;
        }
        acc.x += e * v.x;
        acc.y += e * v.y;
        esum += e;
    }
    if (tid < 129) s[tid] = 0.f;
    __syncthreads();
    atomicAdd(&s[2 * lane], acc.x);
    atomicAdd(&s[2 * lane + 1], acc.y);
    if (lane == 0) atomicAdd(&s[128], esum);
    __syncthreads();
    if (tid < 128) atomicAdd(&st[256 + tid], s[tid]);
    if (tid == 128) atomicAdd(&st[386], s[128]);
}

__global__ void mid_hop_k(const float* __restrict__ W1, const float* __restrict__ W2,
                          const float* __restrict__ pers_rows,
                          const float* __restrict__ pnorms,
                          float* __restrict__ st, int NP) {
    mid_hop_body(W1, W2, pers_rows, pnorms, st, NP);
}

__global__ void finish_hop_k(const float* __restrict__ W, float* __restrict__ st) {
    finish_hop_body(W, st);
}

__global__ void final_cands(const float* __restrict__ crows,
                            const float* __restrict__ cnorms,
                            const float* __restrict__ st,
                            float* __restrict__ out, int N) {
    int lane = threadIdx.x & 63;
    int gw = (int)((blockIdx.x * blockDim.x + threadIdx.x) >> 6);
    int nw = (int)((gridDim.x * blockDim.x) >> 6);
    float2 q = *(const float2*)(st + 2 * lane);
    float qn = st[384];
    for (int i = gw; i < N; i += nw) {
        const float2 c = *(const float2*)(crows + (long)i * D + 2 * lane);
        float dot = wave_sum(c.x * q.x + c.y * q.y);
        if (lane == 0) out[i] = dot / fmaxf(cnorms[i] * qn, EPS);
    }
}

static inline size_t align16(size_t b) { return (b + 15) & ~(size_t)15; }

extern "C" void kernel_launch(void* const* d_in, const int* in_sizes, int n_in,
                              void* d_out, int out_size, void* d_ws, size_t ws_size,
                              hipStream_t stream) {
    const int* xs = (const int*)d_in[0];
    const int* cands = (const int*)d_in[1];
    const int* pers = (const int*)d_in[2];
    const int* keys = (const int*)d_in[3];
    const int* values = (const int*)d_in[4];
    const float* semb = (const float*)d_in[6];
    const float* cemb = (const float*)d_in[7];
    const float* RW = (const float*)d_in[8];
    const float* R2W = (const float*)d_in[9];
    float* out = (float*)d_out;

    const int L = 20;
    const int LQ = in_sizes[0];
    const int VD = in_sizes[6];         // V*D
    const int NMEM = in_sizes[3] / L;   // 65536
    const int NCAND = in_sizes[1] / L;  // 10000
    const int NPERS = in_sizes[2] / L;  // 20

    size_t need = align16((size_t)VD * 2) + 2 * align16((size_t)NMEM * D * 2) +
                  align16((size_t)NMEM * 4) + align16((size_t)NCAND * D * 4) +
                  align16((size_t)NCAND * 4) + align16((size_t)NPERS * D * 4) +
                  align16((size_t)NPERS * 4) + 512 * 4;
    bool stored = (d_ws != nullptr) && (ws_size >= need);

    char* base = (char*)d_ws;
    u16 *tbl16 = nullptr, *kb = nullptr, *vb = nullptr;
    float* knorms = nullptr;
    if (stored) {
        tbl16 = (u16*)base; base += align16((size_t)VD * 2);
        kb = (u16*)base;    base += align16((size_t)NMEM * D * 2);
        vb = (u16*)base;    base += align16((size_t)NMEM * D * 2);
        knorms = (float*)base; base += align16((size_t)NMEM * 4);
    }
    float* enc_cands = (float*)base; base += align16((size_t)NCAND * D * 4);
    float* cnorms = (float*)base;    base += align16((size_t)NCAND * 4);
    float* enc_pers = (float*)base;  base += align16((size_t)NPERS * D * 4);
    float* pnorms = (float*)base;    base += align16((size_t)NPERS * 4);
    float* st = (float*)base;

    const int THR = 256;

    // ---------------- primary: single cooperative dispatch ----------------
    if (stored && NMEM % 2 == 0 && (VD & 3) == 0) {
        int dev = 0;
        (void)hipGetDevice(&dev);
        int ncu = 0;
        (void)hipDeviceGetAttribute(&ncu, hipDeviceAttributeMultiprocessorCount, dev);
        if (ncu <= 0) ncu = 256;
        int nbpc = 0;
        hipError_t oe =
            hipOccupancyMaxActiveBlocksPerMultiprocessor(&nbpc, fused_all, THR, 0);
        int G = nbpc * ncu;
        if (G > 1024) G = 1024;
        if (oe == hipSuccess && G >= 8) {
            FusedArgs fa;
            fa.xs = xs; fa.cands = cands; fa.pers = pers; fa.keys = keys;
            fa.values = values; fa.semb = semb; fa.cemb = cemb; fa.RW = RW;
            fa.R2W = R2W; fa.out = out; fa.tbl16 = tbl16; fa.kb = kb; fa.vb = vb;
            fa.knorms = knorms; fa.enc_cands = enc_cands; fa.cnorms = cnorms;
            fa.enc_pers = enc_pers; fa.pnorms = pnorms; fa.st = st;
            fa.n4 = VD / 4; fa.NMEM = NMEM; fa.NCAND = NCAND; fa.NPERS = NPERS;
            fa.LQ = LQ;
            void* kargs[] = {(void*)&fa};
            hipError_t le = hipLaunchCooperativeKernel(
                fused_all, dim3(G), dim3(THR), kargs, 0, stream);
            if (le == hipSuccess) {
                (void)n_in; (void)out_size;
                return;
            }
        }
        // fall through to multi-kernel path on any failure
    }

    // ---------------- fallback: round-3 multi-kernel path ----------------
    if (stored) {
        int n4 = VD / 4;
        table_to_bf16<<<(n4 + THR - 1) / THR, THR, 0, stream>>>(
            (const float4*)semb, (ushort4*)tbl16, n4);
        int npair = (NMEM + 1) / 2;
        encode_kv_bf16<20><<<(npair + 3) / 4, THR, 0, stream>>>(
            tbl16, keys, values, NMEM, kb, vb, knorms);
    }
    {
        int npair = (NCAND + 1) / 2;
        encode_pairs<20><<<(npair + 3) / 4, THR, 0, stream>>>(
            cemb, cands, NCAND, enc_cands, cnorms);
    }
    encode_small<<<1, THR, 0, stream>>>(semb, pers, NPERS, L, xs, LQ,
                                        enc_pers, pnorms, st);

    persona_hop_k<<<1, THR, 0, stream>>>(enc_pers, pnorms, RW, st, NPERS);
    if (stored)
        big_att_bf16_k<<<1024, THR, 0, stream>>>(kb, knorms, vb, st, NMEM);
    else
        big_att_rc<<<1024, THR, 0, stream>>>(semb, keys, values, st, NMEM, L);

    mid_hop_k<<<1, THR, 0, stream>>>(RW, R2W, enc_pers, pnorms, st, NPERS);
    if (stored)
        big_att_bf16_k<<<1024, THR, 0, stream>>>(kb, knorms, vb, st, NMEM);
    else
        big_att_rc<<<1024, THR, 0, stream>>>(semb, keys, values, st, NMEM, L);
    finish_hop_k<<<1, THR, 0, stream>>>(R2W, st);

    final_cands<<<(NCAND * 64 + THR - 1) / THR, THR, 0, stream>>>(
        enc_cands, cnorms, st, out, NCAND);

    (void)n_in; (void)out_size;
}

// Round 5
// 414.132 us; speedup vs baseline: 2.0401x; 2.0401x over previous
//
#include <hip/hip_runtime.h>
#include <math.h>
#include <stdint.h>

#define D 128
#define EPS 1e-6f
typedef unsigned short u16;

// ---------------------------------------------------------------------------
// state layout (floats), 16B-aligned base (dedicated 128B lines for atomics):
//   st[0..127]   : q
//   st[128..255] : q_plus
//   st[256..383] : hop accumulator (atomicAdd targets)
//   st[384]      : ||q||        st[385] : ||q_plus||
//   st[416]      : sum-of-exp accumulator (atomicAdd target, own 128B line)
//   st[448..451] : (as u32) last-block tickets for K1/K2/K3  (memset to 0)
// ---------------------------------------------------------------------------

__device__ __forceinline__ float wave_sum(float v) {
#pragma unroll
    for (int off = 32; off > 0; off >>= 1) v += __shfl_xor(v, off, 64);
    return v;
}
__device__ __forceinline__ float halfwave_sum(float v) {
#pragma unroll
    for (int off = 16; off > 0; off >>= 1) v += __shfl_xor(v, off, 32);
    return v;
}

__device__ __forceinline__ float bf2f(u16 h) {
    union { unsigned u; float f; } x;
    x.u = ((unsigned)h) << 16;
    return x.f;
}
__device__ __forceinline__ u16 f2bf(float f) {  // round-to-nearest-even
    union { float f; unsigned u; } x;
    x.f = f;
    unsigned u = x.u;
    return (u16)((u + 0x7fff + ((u >> 16) & 1)) >> 16);
}

__device__ __forceinline__ float agent_load(const float* p) {
    return __hip_atomic_load(p, __ATOMIC_RELAXED, __HIP_MEMORY_SCOPE_AGENT);
}

// rocPRIM-style last-block ticket. Returns true in exactly one block, after
// all blocks have passed this point's preceding memory operations.
__device__ __forceinline__ bool last_block_ticket(unsigned* tick, unsigned nblocks) {
    __shared__ unsigned lastflag;
    __syncthreads();  // drains each thread's outstanding vmem (incl. atomics)
    if (threadIdx.x == 0) {
        __threadfence();  // device-scope release of this block's prior writes
        unsigned old = __hip_atomic_fetch_add(tick, 1u, __ATOMIC_ACQ_REL,
                                              __HIP_MEMORY_SCOPE_AGENT);
        lastflag = (old == nblocks - 1u) ? 1u : 0u;
    }
    __syncthreads();
    return lastflag != 0u;
}

// ===========================================================================
// Block-level (256-thread) hop bodies.
// ===========================================================================

__device__ void persona_hop_body(const float* __restrict__ pers_rows,
                                 const float* __restrict__ pnorms,
                                 const float* __restrict__ W,
                                 float* __restrict__ st, int NP) {
    __shared__ float qsh[D];
    __shared__ float att[64];
    __shared__ float qh[D];
    __shared__ float red[2];
    int tid = threadIdx.x;
    if (tid < D) qsh[tid] = st[tid];
    __syncthreads();
    if (tid < NP) {
        float dot = 0.f;
        for (int d2 = 0; d2 < D; ++d2) dot += pers_rows[tid * D + d2] * qsh[d2];
        att[tid] = dot / fmaxf(pnorms[tid] * st[384], EPS);
    }
    __syncthreads();
    if (tid == 0) {
        float m = -1e30f;
        for (int p = 0; p < NP; ++p) m = fmaxf(m, att[p]);
        float s = 0.f;
        for (int p = 0; p < NP; ++p) { att[p] = __expf(att[p] - m); s += att[p]; }
        float inv = 1.f / s;
        for (int p = 0; p < NP; ++p) att[p] *= inv;
    }
    __syncthreads();
    if (tid < D) {
        float h = 0.f;
        for (int p = 0; p < NP; ++p) h += att[p] * pers_rows[p * D + tid];
        qh[tid] = qsh[tid] + h;
    }
    __syncthreads();
    if (tid < D) {
        float qp = 0.f;
        for (int d2 = 0; d2 < D; ++d2) qp += W[tid * D + d2] * qh[d2];
        st[128 + tid] = qp;
        float sq = wave_sum(qp * qp);
        if ((tid & 63) == 0) red[tid >> 6] = sq;
    }
    __syncthreads();
    if (tid == 0) st[385] = sqrtf(red[0] + red[1]);
    if (tid < 128) st[256 + tid] = 0.f;  // zero accumulators for next att
    if (tid == 0) st[416] = 0.f;
}

// Winner of K2: finish hop1 (W1) then persona att + q_plus for hop2 (W2).
// Accumulators read with agent-scope atomic loads (written by device atomics).
__device__ void mid_hop_body(const float* __restrict__ W1,
                             const float* __restrict__ W2,
                             const float* __restrict__ pers_rows,
                             const float* __restrict__ pnorms,
                             float* __restrict__ st, int NP) {
    __shared__ float qh[D];
    __shared__ float qsh[D];
    __shared__ float att[64];
    __shared__ float red[2];
    int tid = threadIdx.x;
    __shared__ float esum_s;
    if (tid == 0) esum_s = agent_load(&st[416]);
    __syncthreads();
    if (tid < D) {
        float inv = 1.f / esum_s;
        qh[tid] = st[128 + tid] + agent_load(&st[256 + tid]) * inv;
    }
    __syncthreads();
    if (tid < D) {
        float qn = 0.f;
        for (int d2 = 0; d2 < D; ++d2) qn += W1[tid * D + d2] * qh[d2];
        qsh[tid] = qn;
        st[tid] = qn;
        float sq = wave_sum(qn * qn);
        if ((tid & 63) == 0) red[tid >> 6] = sq;
    }
    __syncthreads();
    float qnorm = sqrtf(red[0] + red[1]);
    if (tid == 0) st[384] = qnorm;
    if (tid < NP) {
        float dot = 0.f;
        for (int d2 = 0; d2 < D; ++d2) dot += pers_rows[tid * D + d2] * qsh[d2];
        att[tid] = dot / fmaxf(pnorms[tid] * qnorm, EPS);
    }
    __syncthreads();
    if (tid == 0) {
        float m = -1e30f;
        for (int p = 0; p < NP; ++p) m = fmaxf(m, att[p]);
        float s = 0.f;
        for (int p = 0; p < NP; ++p) { att[p] = __expf(att[p] - m); s += att[p]; }
        float is = 1.f / s;
        for (int p = 0; p < NP; ++p) att[p] *= is;
    }
    __syncthreads();
    if (tid < D) {
        float h = 0.f;
        for (int p = 0; p < NP; ++p) h += att[p] * pers_rows[p * D + tid];
        qh[tid] = qsh[tid] + h;
    }
    __syncthreads();
    if (tid < D) {
        float qp = 0.f;
        for (int d2 = 0; d2 < D; ++d2) qp += W2[tid * D + d2] * qh[d2];
        st[128 + tid] = qp;
        float sq2 = wave_sum(qp * qp);
        if ((tid & 63) == 0) red[tid >> 6] = sq2;
    }
    __syncthreads();
    if (tid == 0) st[385] = sqrtf(red[0] + red[1]);
    if (tid < 128) st[256 + tid] = 0.f;  // zero accumulators for hop 2
    if (tid == 0) st[416] = 0.f;
}

__device__ void finish_hop_body(const float* __restrict__ W,
                                float* __restrict__ st) {
    __shared__ float qh[D];
    __shared__ float red[2];
    __shared__ float esum_s;
    int tid = threadIdx.x;
    if (tid == 0) esum_s = agent_load(&st[416]);
    __syncthreads();
    if (tid < D) {
        float inv = 1.f / esum_s;
        qh[tid] = st[128 + tid] + agent_load(&st[256 + tid]) * inv;
    }
    __syncthreads();
    if (tid < D) {
        float qn = 0.f;
        for (int d2 = 0; d2 < D; ++d2) qn += W[tid * D + d2] * qh[d2];
        st[tid] = qn;
        float sq = wave_sum(qn * qn);
        if ((tid & 63) == 0) red[tid >> 6] = sq;
    }
    __syncthreads();
    if (tid == 0) st[384] = sqrtf(red[0] + red[1]);
}

// Block tail of attention: merge per-thread acc into LDS, then one set of
// global device-scope atomics into st[256..383] and st[416].
__device__ void att_block_reduce(float4 acc, float esum, float* __restrict__ st) {
    __shared__ float s[132];
    int tid = threadIdx.x;
    int lane = tid & 63;
    int half = lane >> 5, hl = lane & 31;
    acc.x += __shfl_xor(acc.x, 32, 64);
    acc.y += __shfl_xor(acc.y, 32, 64);
    acc.z += __shfl_xor(acc.z, 32, 64);
    acc.w += __shfl_xor(acc.w, 32, 64);
    esum += __shfl_xor(esum, 32, 64);
    if (tid < 132) s[tid] = 0.f;
    __syncthreads();
    if (half == 0) {
        atomicAdd(&s[4 * hl + 0], acc.x);
        atomicAdd(&s[4 * hl + 1], acc.y);
        atomicAdd(&s[4 * hl + 2], acc.z);
        atomicAdd(&s[4 * hl + 3], acc.w);
        if (hl == 0) atomicAdd(&s[128], esum);
    }
    __syncthreads();
    if (tid < 128) atomicAdd(&st[256 + tid], s[tid]);
    if (tid == 128) atomicAdd(&st[416], s[128]);
}

// ===========================================================================
// K1: bf16 table convert (all blocks); winner encodes persona + q (fp32 from
// semb) and runs persona hop 1.
// ===========================================================================
__global__ void k1_prep(const float* __restrict__ semb, int n4,
                        u16* __restrict__ tbl16,
                        const int* __restrict__ pers, int NP,
                        const int* __restrict__ xs, int LQ,
                        const float* __restrict__ RW,
                        float* __restrict__ enc_pers, float* __restrict__ pnorms,
                        float* __restrict__ st, unsigned* tick, unsigned nblocks) {
    {
        const int gtid = blockIdx.x * blockDim.x + threadIdx.x;
        const int gthreads = gridDim.x * blockDim.x;
        const float4* src = (const float4*)semb;
        ushort4* dst = (ushort4*)tbl16;
        for (int i = gtid; i < n4; i += gthreads) {
            float4 v = src[i];
            ushort4 o;
            o.x = f2bf(v.x); o.y = f2bf(v.y); o.z = f2bf(v.z); o.w = f2bf(v.w);
            dst[i] = o;
        }
    }
    if (last_block_ticket(tick, nblocks)) {
        const int tid = threadIdx.x;
        const int lane = tid & 63;
        const int half = lane >> 5;
        const int hl = lane & 31;
        const int w = tid >> 6;  // wave in block (4 waves)
        const int npr = NP + 1;  // +1 virtual row = q
        const int npairs = (npr + 1) >> 1;
        for (int p = w; p < npairs; p += 4) {
            const int row = 2 * p + half;
            const bool valid = row < npr;
            const int rowc = valid ? (row < NP ? row : NP) : NP;  // clamp to q slot
            const bool isq = (rowc == NP);
            const int* ids = isq ? xs : (pers + (long)rowc * 20);
            const int L = isq ? LQ : 20;
            int myid = 0;
            if (hl < L) myid = ids[hl];
            float4 acc = {0.f, 0.f, 0.f, 0.f};
            for (int t = 0; t < L; ++t) {
                const int idx = __shfl(myid, (half << 5) + t, 64);
                const float4 e = *(const float4*)(semb + (long)idx * D + 4 * hl);
                acc.x += e.x; acc.y += e.y; acc.z += e.z; acc.w += e.w;
            }
            if (valid) {
                float* outp = isq ? st : (enc_pers + (long)rowc * D);
                *(float4*)(outp + 4 * hl) = acc;
                float sq = acc.x * acc.x + acc.y * acc.y + acc.z * acc.z + acc.w * acc.w;
                sq = halfwave_sum(sq);
                if (hl == 0) {
                    if (isq) st[384] = sqrtf(sq);
                    else pnorms[rowc] = sqrtf(sq);
                }
            }
        }
        __syncthreads();
        persona_hop_body(enc_pers, pnorms, RW, st, NP);
    }
}

// ===========================================================================
// K2: kv gather (bf16 table) + attention hop 1 fused. Each block attends over
// the rows it just built (fp32, pre-rounding); stores bf16 kb/vb + knorms for
// hop 2. Winner runs mid-hop.
// ===========================================================================
__global__ __launch_bounds__(256) void k2_kv_att1(
    const u16* __restrict__ tbl, const int* __restrict__ kids,
    const int* __restrict__ vids, int N, u16* __restrict__ kb,
    u16* __restrict__ vb, float* __restrict__ knorms,
    const float* __restrict__ W1, const float* __restrict__ W2,
    const float* __restrict__ enc_pers, const float* __restrict__ pnorms,
    int NP, float* __restrict__ st, unsigned* tick, unsigned nblocks) {
    const int tid = threadIdx.x;
    const int lane = tid & 63;
    const int half = lane >> 5;
    const int hl = lane & 31;
    const int gw = (int)((blockIdx.x * blockDim.x + tid) >> 6);
    const int nw = (int)((gridDim.x * blockDim.x) >> 6);
    const float4 qp = *(const float4*)(st + 128 + 4 * hl);
    const float qpn = st[385];
    float4 hacc = {0.f, 0.f, 0.f, 0.f};
    float esum = 0.f;
    const int npair = N >> 1;  // N even
    for (int p = gw; p < npair; p += nw) {
        const int row = 2 * p + half;
        int kid = 0, vid = 0;
        if (hl < 20) {
            kid = kids[(long)row * 20 + hl];
            vid = vids[(long)row * 20 + hl];
        }
        float4 ka = {0.f, 0.f, 0.f, 0.f}, va = {0.f, 0.f, 0.f, 0.f};
#pragma unroll
        for (int t = 0; t < 20; ++t) {
            const int ki = __shfl(kid, (half << 5) + t, 64);
            const int vi = __shfl(vid, (half << 5) + t, 64);
            const ushort4 ke = *(const ushort4*)(tbl + (long)ki * D + 4 * hl);
            const ushort4 ve = *(const ushort4*)(tbl + (long)vi * D + 4 * hl);
            ka.x += bf2f(ke.x); ka.y += bf2f(ke.y);
            ka.z += bf2f(ke.z); ka.w += bf2f(ke.w);
            va.x += bf2f(ve.x); va.y += bf2f(ve.y);
            va.z += bf2f(ve.z); va.w += bf2f(ve.w);
        }
        // store bf16 rows + norm for hop 2
        ushort4 ko, vo;
        ko.x = f2bf(ka.x); ko.y = f2bf(ka.y); ko.z = f2bf(ka.z); ko.w = f2bf(ka.w);
        vo.x = f2bf(va.x); vo.y = f2bf(va.y); vo.z = f2bf(va.z); vo.w = f2bf(va.w);
        *(ushort4*)(kb + (long)row * D + 4 * hl) = ko;
        *(ushort4*)(vb + (long)row * D + 4 * hl) = vo;
        float nsq = halfwave_sum(ka.x * ka.x + ka.y * ka.y + ka.z * ka.z + ka.w * ka.w);
        float kn = sqrtf(nsq);
        if (hl == 0) knorms[row] = kn;
        // attention hop 1 on the fp32 rows, in registers
        float dot = halfwave_sum(ka.x * qp.x + ka.y * qp.y + ka.z * qp.z + ka.w * qp.w);
        const float c = dot / fmaxf(kn * qpn, EPS);
        const float e = __expf(c);
        hacc.x += e * va.x; hacc.y += e * va.y;
        hacc.z += e * va.z; hacc.w += e * va.w;
        if (hl == 0) esum += e;
    }
    att_block_reduce(hacc, esum, st);
    if (last_block_ticket(tick, nblocks)) {
        __threadfence();
        mid_hop_body(W1, W2, enc_pers, pnorms, st, NP);
    }
}

// ===========================================================================
// K3: attention hop 2 over stored bf16 rows. Winner runs finish-hop.
// ===========================================================================
__global__ __launch_bounds__(256) void k3_att2(
    const u16* __restrict__ krows, const float* __restrict__ knorms,
    const u16* __restrict__ vrows, int N, const float* __restrict__ W2,
    float* __restrict__ st, unsigned* tick, unsigned nblocks) {
    const int tid = threadIdx.x;
    const int lane = tid & 63;
    const int half = lane >> 5;
    const int hl = lane & 31;
    const int gw = (int)((blockIdx.x * blockDim.x + tid) >> 6);
    const int nw = (int)((gridDim.x * blockDim.x) >> 6);
    const float4 qp = *(const float4*)(st + 128 + 4 * hl);
    const float qpn = st[385];
    float4 acc = {0.f, 0.f, 0.f, 0.f};
    float esum = 0.f;
    const int npair = N >> 1;
    for (int p = gw; p < npair; p += nw) {
        const int i = 2 * p + half;
        const ushort4 kh = *(const ushort4*)(krows + (long)i * D + 4 * hl);
        float dot = bf2f(kh.x) * qp.x + bf2f(kh.y) * qp.y +
                    bf2f(kh.z) * qp.z + bf2f(kh.w) * qp.w;
        dot = halfwave_sum(dot);
        const float c = dot / fmaxf(knorms[i] * qpn, EPS);
        const float e = __expf(c);
        const ushort4 vh = *(const ushort4*)(vrows + (long)i * D + 4 * hl);
        acc.x += e * bf2f(vh.x);
        acc.y += e * bf2f(vh.y);
        acc.z += e * bf2f(vh.z);
        acc.w += e * bf2f(vh.w);
        if (hl == 0) esum += e;
    }
    att_block_reduce(acc, esum, st);
    if (last_block_ticket(tick, nblocks)) {
        __threadfence();
        finish_hop_body(W2, st);
    }
}

// ===========================================================================
// K4: candidate gather + cosine, fused (enc_cands never materialized).
// ===========================================================================
__global__ void k4_final(const float* __restrict__ cemb,
                         const int* __restrict__ cands, int NC,
                         const float* __restrict__ st, float* __restrict__ out) {
    const int lane = threadIdx.x & 63;
    const int half = lane >> 5;
    const int hl = lane & 31;
    const int gw = (int)((blockIdx.x * blockDim.x + threadIdx.x) >> 6);
    const int nw = (int)((gridDim.x * blockDim.x) >> 6);
    const float4 q4 = *(const float4*)(st + 4 * hl);
    const float qn = st[384];
    const int npair = (NC + 1) >> 1;
    for (int p = gw; p < npair; p += nw) {
        const int row = 2 * p + half;
        const bool valid = row < NC;
        const int rowc = valid ? row : (NC - 1);
        int myid = 0;
        if (hl < 20) myid = cands[(long)rowc * 20 + hl];
        float4 acc = {0.f, 0.f, 0.f, 0.f};
#pragma unroll
        for (int t = 0; t < 20; ++t) {
            const int idx = __shfl(myid, (half << 5) + t, 64);
            const float4 e = *(const float4*)(cemb + (long)idx * D + 4 * hl);
            acc.x += e.x; acc.y += e.y; acc.z += e.z; acc.w += e.w;
        }
        float dot = halfwave_sum(acc.x * q4.x + acc.y * q4.y +
                                 acc.z * q4.z + acc.w * q4.w);
        float nsq = halfwave_sum(acc.x * acc.x + acc.y * acc.y +
                                 acc.z * acc.z + acc.w * acc.w);
        if (valid && hl == 0) out[row] = dot / fmaxf(sqrtf(nsq) * qn, EPS);
    }
}

// ===========================================================================
// Fallback path (workspace too small): fp32 on-the-fly gather, multi-kernel.
// ===========================================================================
__global__ void encode_small(const float* __restrict__ emb,
                             const int* __restrict__ pers, int NP, int LP,
                             const int* __restrict__ xs, int LQ,
                             float* __restrict__ pers_rows,
                             float* __restrict__ pnorms,
                             float* __restrict__ st) {
    int lane = threadIdx.x & 63;
    int w = threadIdx.x >> 6;
    for (int i = w; i <= NP; i += 4) {
        const int* ids;
        int L;
        float* out;
        float* nrm;
        if (i < NP) { ids = pers + (long)i * LP; L = LP; out = pers_rows + (long)i * D; nrm = pnorms + i; }
        else        { ids = xs; L = LQ; out = st; nrm = st + 384; }
        float2 acc = {0.f, 0.f};
        for (int t = 0; t < L; ++t) {
            int idx = ids[t];
            const float2 e = *(const float2*)(emb + (long)idx * D + 2 * lane);
            acc.x += e.x;
            acc.y += e.y;
        }
        *(float2*)(out + 2 * lane) = acc;
        float sq = wave_sum(acc.x * acc.x + acc.y * acc.y);
        if (lane == 0) *nrm = sqrtf(sq);
    }
}

__global__ void persona_hop_k(const float* __restrict__ pers_rows,
                              const float* __restrict__ pnorms,
                              const float* __restrict__ W,
                              float* __restrict__ st, int NP) {
    persona_hop_body(pers_rows, pnorms, W, st, NP);
}

__global__ void big_att_rc(const float* __restrict__ emb,
                           const int* __restrict__ kids,
                           const int* __restrict__ vids,
                           float* __restrict__ st, int N) {
    const int tid = threadIdx.x;
    const int lane = tid & 63;
    const int half = lane >> 5;
    const int hl = lane & 31;
    const int gw = (int)((blockIdx.x * blockDim.x + tid) >> 6);
    const int nw = (int)((gridDim.x * blockDim.x) >> 6);
    const float4 qp = *(const float4*)(st + 128 + 4 * hl);
    const float qpn = st[385];
    float4 hacc = {0.f, 0.f, 0.f, 0.f};
    float esum = 0.f;
    const int npair = (N + 1) >> 1;
    for (int p = gw; p < npair; p += nw) {
        const int row = 2 * p + half;
        const bool valid = row < N;
        const int rowc = valid ? row : (N - 1);
        int kid = 0, vid = 0;
        if (hl < 20) {
            kid = kids[(long)rowc * 20 + hl];
            vid = vids[(long)rowc * 20 + hl];
        }
        float4 ka = {0.f, 0.f, 0.f, 0.f}, va = {0.f, 0.f, 0.f, 0.f};
#pragma unroll
        for (int t = 0; t < 20; ++t) {
            const int ki = __shfl(kid, (half << 5) + t, 64);
            const int vi = __shfl(vid, (half << 5) + t, 64);
            const float4 ke = *(const float4*)(emb + (long)ki * D + 4 * hl);
            const float4 ve = *(const float4*)(emb + (long)vi * D + 4 * hl);
            ka.x += ke.x; ka.y += ke.y; ka.z += ke.z; ka.w += ke.w;
            va.x += ve.x; va.y += ve.y; va.z += ve.z; va.w += ve.w;
        }
        float nsq = halfwave_sum(ka.x * ka.x + ka.y * ka.y + ka.z * ka.z + ka.w * ka.w);
        float dot = halfwave_sum(ka.x * qp.x + ka.y * qp.y + ka.z * qp.z + ka.w * qp.w);
        const float c = dot / fmaxf(sqrtf(nsq) * qpn, EPS);
        float e = __expf(c);
        if (!valid) e = 0.f;
        hacc.x += e * va.x; hacc.y += e * va.y;
        hacc.z += e * va.z; hacc.w += e * va.w;
        if (hl == 0) esum += e;
    }
    att_block_reduce(hacc, esum, st);
}

__global__ void mid_hop_k(const float* __restrict__ W1, const float* __restrict__ W2,
                          const float* __restrict__ pers_rows,
                          const float* __restrict__ pnorms,
                          float* __restrict__ st, int NP) {
    mid_hop_body(W1, W2, pers_rows, pnorms, st, NP);
}

__global__ void finish_hop_k(const float* __restrict__ W, float* __restrict__ st) {
    finish_hop_body(W, st);
}

static inline size_t align16(size_t b) { return (b + 15) & ~(size_t)15; }

extern "C" void kernel_launch(void* const* d_in, const int* in_sizes, int n_in,
                              void* d_out, int out_size, void* d_ws, size_t ws_size,
                              hipStream_t stream) {
    const int* xs = (const int*)d_in[0];
    const int* cands = (const int*)d_in[1];
    const int* pers = (const int*)d_in[2];
    const int* keys = (const int*)d_in[3];
    const int* values = (const int*)d_in[4];
    const float* semb = (const float*)d_in[6];
    const float* cemb = (const float*)d_in[7];
    const float* RW = (const float*)d_in[8];
    const float* R2W = (const float*)d_in[9];
    float* out = (float*)d_out;

    const int L = 20;
    const int LQ = in_sizes[0];
    const int VD = in_sizes[6];         // V*D
    const int NMEM = in_sizes[3] / L;   // 65536
    const int NCAND = in_sizes[1] / L;  // 10000
    const int NPERS = in_sizes[2] / L;  // 20

    size_t need = align16((size_t)VD * 2) + 2 * align16((size_t)NMEM * D * 2) +
                  align16((size_t)NMEM * 4) + align16((size_t)NPERS * D * 4) +
                  align16((size_t)NPERS * 4) + 512 * 4;
    bool stored = (d_ws != nullptr) && (ws_size >= need) && (NMEM % 2 == 0) &&
                  ((VD & 3) == 0);

    const int THR = 256;

    if (stored) {
        char* base = (char*)d_ws;
        u16* tbl16 = (u16*)base;  base += align16((size_t)VD * 2);
        u16* kb = (u16*)base;     base += align16((size_t)NMEM * D * 2);
        u16* vb = (u16*)base;     base += align16((size_t)NMEM * D * 2);
        float* knorms = (float*)base;   base += align16((size_t)NMEM * 4);
        float* enc_pers = (float*)base; base += align16((size_t)NPERS * D * 4);
        float* pnorms = (float*)base;   base += align16((size_t)NPERS * 4);
        float* st = (float*)base;
        unsigned* ticks = (unsigned*)(st + 448);

        hipMemsetAsync((void*)ticks, 0, 16, stream);

        const unsigned G1 = 1024, G2 = 1024, G3 = 1024;
        k1_prep<<<G1, THR, 0, stream>>>(semb, VD / 4, tbl16, pers, NPERS, xs, LQ,
                                        RW, enc_pers, pnorms, st, &ticks[0], G1);
        k2_kv_att1<<<G2, THR, 0, stream>>>(tbl16, keys, values, NMEM, kb, vb,
                                           knorms, RW, R2W, enc_pers, pnorms,
                                           NPERS, st, &ticks[1], G2);
        k3_att2<<<G3, THR, 0, stream>>>(kb, knorms, vb, NMEM, R2W, st,
                                        &ticks[2], G3);
        int nblk4 = (((NCAND + 1) / 2) + 3) / 4;
        k4_final<<<nblk4, THR, 0, stream>>>(cemb, cands, NCAND, st, out);
        (void)n_in; (void)out_size;
        return;
    }

    // -------- fallback: fp32 on-the-fly gather, multi-kernel --------
    char* base = (char*)d_ws;
    float* enc_pers = (float*)base; base += align16((size_t)NPERS * D * 4);
    float* pnorms = (float*)base;   base += align16((size_t)NPERS * 4);
    float* st = (float*)base;

    encode_small<<<1, THR, 0, stream>>>(semb, pers, NPERS, L, xs, LQ,
                                        enc_pers, pnorms, st);
    persona_hop_k<<<1, THR, 0, stream>>>(enc_pers, pnorms, RW, st, NPERS);
    big_att_rc<<<1024, THR, 0, stream>>>(semb, keys, values, st, NMEM);
    mid_hop_k<<<1, THR, 0, stream>>>(RW, R2W, enc_pers, pnorms, st, NPERS);
    big_att_rc<<<1024, THR, 0, stream>>>(semb, keys, values, st, NMEM);
    finish_hop_k<<<1, THR, 0, stream>>>(R2W, st);
    int nblk4 = (((NCAND + 1) / 2) + 3) / 4;
    k4_final<<<nblk4, THR, 0, stream>>>(cemb, cands, NCAND, st, out);

    (void)n_in; (void)out_size;
}

// Round 6
// 409.912 us; speedup vs baseline: 2.0611x; 1.0103x over previous
//
#include <hip/hip_runtime.h>
#include <math.h>
#include <stdint.h>

#define D 128
#define EPS 1e-6f
typedef unsigned short u16;

// ---------------------------------------------------------------------------
// state layout (floats), 16B-aligned base:
//   st[0..127]   : q
//   st[128..255] : q_plus
//   st[256..383] : hop accumulator (device atomicAdd targets)
//   st[384]      : ||q||        st[385] : ||q_plus||
//   st[416]      : sum-of-exp accumulator (own 128B line)
//   st[448..451] : (as u32) last-block tickets (memset to 0)
// ---------------------------------------------------------------------------

__device__ __forceinline__ float wave_sum(float v) {
#pragma unroll
    for (int off = 32; off > 0; off >>= 1) v += __shfl_xor(v, off, 64);
    return v;
}
__device__ __forceinline__ float halfwave_sum(float v) {
#pragma unroll
    for (int off = 16; off > 0; off >>= 1) v += __shfl_xor(v, off, 32);
    return v;
}

__device__ __forceinline__ float bf2f(u16 h) {
    union { unsigned u; float f; } x;
    x.u = ((unsigned)h) << 16;
    return x.f;
}
__device__ __forceinline__ u16 f2bf(float f) {  // round-to-nearest-even
    union { float f; unsigned u; } x;
    x.f = f;
    unsigned u = x.u;
    return (u16)((u + 0x7fff + ((u >> 16) & 1)) >> 16);
}

__device__ __forceinline__ float agent_load(const float* p) {
    return __hip_atomic_load(p, __ATOMIC_RELAXED, __HIP_MEMORY_SCOPE_AGENT);
}

// rocPRIM-style last-block ticket.
__device__ __forceinline__ bool last_block_ticket(unsigned* tick, unsigned nblocks) {
    __shared__ unsigned lastflag;
    __syncthreads();
    if (threadIdx.x == 0) {
        __threadfence();
        unsigned old = __hip_atomic_fetch_add(tick, 1u, __ATOMIC_ACQ_REL,
                                              __HIP_MEMORY_SCOPE_AGENT);
        lastflag = (old == nblocks - 1u) ? 1u : 0u;
    }
    __syncthreads();
    return lastflag != 0u;
}

// ===========================================================================
// Block-level (256-thread) hop bodies.
// ===========================================================================

__device__ void persona_hop_body(const float* __restrict__ pers_rows,
                                 const float* __restrict__ pnorms,
                                 const float* __restrict__ W,
                                 float* __restrict__ st, int NP) {
    __shared__ float qsh[D];
    __shared__ float att[64];
    __shared__ float qh[D];
    __shared__ float red[2];
    int tid = threadIdx.x;
    if (tid < D) qsh[tid] = st[tid];
    __syncthreads();
    if (tid < NP) {
        float dot = 0.f;
        for (int d2 = 0; d2 < D; ++d2) dot += pers_rows[tid * D + d2] * qsh[d2];
        att[tid] = dot / fmaxf(pnorms[tid] * st[384], EPS);
    }
    __syncthreads();
    if (tid == 0) {
        float m = -1e30f;
        for (int p = 0; p < NP; ++p) m = fmaxf(m, att[p]);
        float s = 0.f;
        for (int p = 0; p < NP; ++p) { att[p] = __expf(att[p] - m); s += att[p]; }
        float inv = 1.f / s;
        for (int p = 0; p < NP; ++p) att[p] *= inv;
    }
    __syncthreads();
    if (tid < D) {
        float h = 0.f;
        for (int p = 0; p < NP; ++p) h += att[p] * pers_rows[p * D + tid];
        qh[tid] = qsh[tid] + h;
    }
    __syncthreads();
    if (tid < D) {
        float qp = 0.f;
        for (int d2 = 0; d2 < D; ++d2) qp += W[tid * D + d2] * qh[d2];
        st[128 + tid] = qp;
        float sq = wave_sum(qp * qp);
        if ((tid & 63) == 0) red[tid >> 6] = sq;
    }
    __syncthreads();
    if (tid == 0) st[385] = sqrtf(red[0] + red[1]);
    if (tid < 128) st[256 + tid] = 0.f;
    if (tid == 0) st[416] = 0.f;
}

__device__ void mid_hop_body(const float* __restrict__ W1,
                             const float* __restrict__ W2,
                             const float* __restrict__ pers_rows,
                             const float* __restrict__ pnorms,
                             float* __restrict__ st, int NP) {
    __shared__ float qh[D];
    __shared__ float qsh[D];
    __shared__ float att[64];
    __shared__ float red[2];
    __shared__ float esum_s;
    int tid = threadIdx.x;
    if (tid == 0) esum_s = agent_load(&st[416]);
    __syncthreads();
    if (tid < D) {
        float inv = 1.f / esum_s;
        qh[tid] = st[128 + tid] + agent_load(&st[256 + tid]) * inv;
    }
    __syncthreads();
    if (tid < D) {
        float qn = 0.f;
        for (int d2 = 0; d2 < D; ++d2) qn += W1[tid * D + d2] * qh[d2];
        qsh[tid] = qn;
        st[tid] = qn;
        float sq = wave_sum(qn * qn);
        if ((tid & 63) == 0) red[tid >> 6] = sq;
    }
    __syncthreads();
    float qnorm = sqrtf(red[0] + red[1]);
    if (tid == 0) st[384] = qnorm;
    if (tid < NP) {
        float dot = 0.f;
        for (int d2 = 0; d2 < D; ++d2) dot += pers_rows[tid * D + d2] * qsh[d2];
        att[tid] = dot / fmaxf(pnorms[tid] * qnorm, EPS);
    }
    __syncthreads();
    if (tid == 0) {
        float m = -1e30f;
        for (int p = 0; p < NP; ++p) m = fmaxf(m, att[p]);
        float s = 0.f;
        for (int p = 0; p < NP; ++p) { att[p] = __expf(att[p] - m); s += att[p]; }
        float is = 1.f / s;
        for (int p = 0; p < NP; ++p) att[p] *= is;
    }
    __syncthreads();
    if (tid < D) {
        float h = 0.f;
        for (int p = 0; p < NP; ++p) h += att[p] * pers_rows[p * D + tid];
        qh[tid] = qsh[tid] + h;
    }
    __syncthreads();
    if (tid < D) {
        float qp = 0.f;
        for (int d2 = 0; d2 < D; ++d2) qp += W2[tid * D + d2] * qh[d2];
        st[128 + tid] = qp;
        float sq2 = wave_sum(qp * qp);
        if ((tid & 63) == 0) red[tid >> 6] = sq2;
    }
    __syncthreads();
    if (tid == 0) st[385] = sqrtf(red[0] + red[1]);
    if (tid < 128) st[256 + tid] = 0.f;
    if (tid == 0) st[416] = 0.f;
}

__device__ void finish_hop_body(const float* __restrict__ W,
                                float* __restrict__ st) {
    __shared__ float qh[D];
    __shared__ float red[2];
    __shared__ float esum_s;
    int tid = threadIdx.x;
    if (tid == 0) esum_s = agent_load(&st[416]);
    __syncthreads();
    if (tid < D) {
        float inv = 1.f / esum_s;
        qh[tid] = st[128 + tid] + agent_load(&st[256 + tid]) * inv;
    }
    __syncthreads();
    if (tid < D) {
        float qn = 0.f;
        for (int d2 = 0; d2 < D; ++d2) qn += W[tid * D + d2] * qh[d2];
        st[tid] = qn;
        float sq = wave_sum(qn * qn);
        if ((tid & 63) == 0) red[tid >> 6] = sq;
    }
    __syncthreads();
    if (tid == 0) st[384] = sqrtf(red[0] + red[1]);
}

// Block tail of attention: LDS merge then one set of global atomics.
__device__ void att_block_reduce(float4 acc, float esum, float* __restrict__ st) {
    __shared__ float s[132];
    int tid = threadIdx.x;
    int lane = tid & 63;
    int half = lane >> 5, hl = lane & 31;
    acc.x += __shfl_xor(acc.x, 32, 64);
    acc.y += __shfl_xor(acc.y, 32, 64);
    acc.z += __shfl_xor(acc.z, 32, 64);
    acc.w += __shfl_xor(acc.w, 32, 64);
    esum += __shfl_xor(esum, 32, 64);
    if (tid < 132) s[tid] = 0.f;
    __syncthreads();
    if (half == 0) {
        atomicAdd(&s[4 * hl + 0], acc.x);
        atomicAdd(&s[4 * hl + 1], acc.y);
        atomicAdd(&s[4 * hl + 2], acc.z);
        atomicAdd(&s[4 * hl + 3], acc.w);
        if (hl == 0) atomicAdd(&s[128], esum);
    }
    __syncthreads();
    if (tid < 128) atomicAdd(&st[256 + tid], s[tid]);
    if (tid == 128) atomicAdd(&st[416], s[128]);
}

// ===========================================================================
// K1: bf16 table convert (grid-stride); ticket winner encodes persona + q
// (fp32 from semb) and runs persona hop 1.
// ===========================================================================
__global__ void k1_prep(const float* __restrict__ semb, int n4,
                        u16* __restrict__ tbl16,
                        const int* __restrict__ pers, int NP,
                        const int* __restrict__ xs, int LQ,
                        const float* __restrict__ RW,
                        float* __restrict__ enc_pers, float* __restrict__ pnorms,
                        float* __restrict__ st, unsigned* tick, unsigned nblocks) {
    {
        const int gtid = blockIdx.x * blockDim.x + threadIdx.x;
        const int gthreads = gridDim.x * blockDim.x;
        const float4* src = (const float4*)semb;
        ushort4* dst = (ushort4*)tbl16;
        for (int i = gtid; i < n4; i += gthreads) {
            float4 v = src[i];
            ushort4 o;
            o.x = f2bf(v.x); o.y = f2bf(v.y); o.z = f2bf(v.z); o.w = f2bf(v.w);
            dst[i] = o;
        }
    }
    if (last_block_ticket(tick, nblocks)) {
        const int tid = threadIdx.x;
        const int lane = tid & 63;
        const int half = lane >> 5;
        const int hl = lane & 31;
        const int w = tid >> 6;
        const int npr = NP + 1;  // +1 virtual row = q
        const int npairs = (npr + 1) >> 1;
        for (int p = w; p < npairs; p += 4) {
            const int row = 2 * p + half;
            const bool valid = row < npr;
            const int rowc = valid ? (row < NP ? row : NP) : NP;
            const bool isq = (rowc == NP);
            const int* ids = isq ? xs : (pers + (long)rowc * 20);
            const int L = isq ? LQ : 20;
            int myid = 0;
            if (hl < L) myid = ids[hl];
            float4 acc = {0.f, 0.f, 0.f, 0.f};
            for (int t = 0; t < L; ++t) {
                const int idx = __shfl(myid, (half << 5) + t, 64);
                const float4 e = *(const float4*)(semb + (long)idx * D + 4 * hl);
                acc.x += e.x; acc.y += e.y; acc.z += e.z; acc.w += e.w;
            }
            if (valid) {
                float* outp = isq ? st : (enc_pers + (long)rowc * D);
                *(float4*)(outp + 4 * hl) = acc;
                float sq = acc.x * acc.x + acc.y * acc.y + acc.z * acc.z + acc.w * acc.w;
                sq = halfwave_sum(sq);
                if (hl == 0) {
                    if (isq) st[384] = sqrtf(sq);
                    else pnorms[rowc] = sqrtf(sq);
                }
            }
        }
        __syncthreads();
        persona_hop_body(enc_pers, pnorms, RW, st, NP);
    }
}

// ===========================================================================
// K2: pure kv gather (bf16 table), full grid = 1 pair/wave (max occupancy).
// Exactly the round-3 structure that measured 73 us / 46% occ.
// ===========================================================================
template <int L>
__global__ void encode_kv_bf16(const u16* __restrict__ tbl,
                               const int* __restrict__ kids,
                               const int* __restrict__ vids, int N,
                               u16* __restrict__ krows, u16* __restrict__ vrows,
                               float* __restrict__ knorms) {
    const int lane = threadIdx.x & 63;
    const int half = lane >> 5;
    const int hl = lane & 31;
    int gw = (int)((blockIdx.x * blockDim.x + threadIdx.x) >> 6);
    int nw = (int)((gridDim.x * blockDim.x) >> 6);
    const int npair = (N + 1) >> 1;
    for (int p = gw; p < npair; p += nw) {
        const int row = 2 * p + half;
        const bool valid = row < N;
        const int rowc = valid ? row : (N - 1);
        int kid = 0, vid = 0;
        if (hl < L) {
            kid = kids[(long)rowc * L + hl];
            vid = vids[(long)rowc * L + hl];
        }
        float4 ka = {0.f, 0.f, 0.f, 0.f}, va = {0.f, 0.f, 0.f, 0.f};
#pragma unroll
        for (int t = 0; t < L; ++t) {
            const int ki = __shfl(kid, (half << 5) + t, 64);
            const int vi = __shfl(vid, (half << 5) + t, 64);
            const ushort4 ke = *(const ushort4*)(tbl + (long)ki * D + 4 * hl);
            const ushort4 ve = *(const ushort4*)(tbl + (long)vi * D + 4 * hl);
            ka.x += bf2f(ke.x); ka.y += bf2f(ke.y);
            ka.z += bf2f(ke.z); ka.w += bf2f(ke.w);
            va.x += bf2f(ve.x); va.y += bf2f(ve.y);
            va.z += bf2f(ve.z); va.w += bf2f(ve.w);
        }
        if (valid) {
            ushort4 ko, vo;
            ko.x = f2bf(ka.x); ko.y = f2bf(ka.y); ko.z = f2bf(ka.z); ko.w = f2bf(ka.w);
            vo.x = f2bf(va.x); vo.y = f2bf(va.y); vo.z = f2bf(va.z); vo.w = f2bf(va.w);
            *(ushort4*)(krows + (long)row * D + 4 * hl) = ko;
            *(ushort4*)(vrows + (long)row * D + 4 * hl) = vo;
        }
        float sq = ka.x * ka.x + ka.y * ka.y + ka.z * ka.z + ka.w * ka.w;
        sq = halfwave_sum(sq);
        if (valid && hl == 0) knorms[row] = sqrtf(sq);
    }
}

// ===========================================================================
// K3/K4: attention over stored bf16 rows; ticket winner runs the hop stage.
// ===========================================================================
__device__ void att_loop(const u16* __restrict__ krows,
                         const float* __restrict__ knorms,
                         const u16* __restrict__ vrows,
                         float* __restrict__ st, int N) {
    const int tid = threadIdx.x;
    const int lane = tid & 63;
    const int half = lane >> 5;
    const int hl = lane & 31;
    const int gw = (int)((blockIdx.x * blockDim.x + tid) >> 6);
    const int nw = (int)((gridDim.x * blockDim.x) >> 6);
    const float4 qp = *(const float4*)(st + 128 + 4 * hl);
    const float qpn = st[385];
    float4 acc = {0.f, 0.f, 0.f, 0.f};
    float esum = 0.f;
    const int npair = N >> 1;
    for (int p = gw; p < npair; p += nw) {
        const int i = 2 * p + half;
        const ushort4 kh = *(const ushort4*)(krows + (long)i * D + 4 * hl);
        float dot = bf2f(kh.x) * qp.x + bf2f(kh.y) * qp.y +
                    bf2f(kh.z) * qp.z + bf2f(kh.w) * qp.w;
        dot = halfwave_sum(dot);
        const float c = dot / fmaxf(knorms[i] * qpn, EPS);
        const float e = __expf(c);
        const ushort4 vh = *(const ushort4*)(vrows + (long)i * D + 4 * hl);
        acc.x += e * bf2f(vh.x);
        acc.y += e * bf2f(vh.y);
        acc.z += e * bf2f(vh.z);
        acc.w += e * bf2f(vh.w);
        if (hl == 0) esum += e;
    }
    att_block_reduce(acc, esum, st);
}

__global__ __launch_bounds__(256) void k3_att1(
    const u16* __restrict__ krows, const float* __restrict__ knorms,
    const u16* __restrict__ vrows, int N,
    const float* __restrict__ W1, const float* __restrict__ W2,
    const float* __restrict__ enc_pers, const float* __restrict__ pnorms,
    int NP, float* __restrict__ st, unsigned* tick, unsigned nblocks) {
    att_loop(krows, knorms, vrows, st, N);
    if (last_block_ticket(tick, nblocks)) {
        __threadfence();
        mid_hop_body(W1, W2, enc_pers, pnorms, st, NP);
    }
}

__global__ __launch_bounds__(256) void k4_att2(
    const u16* __restrict__ krows, const float* __restrict__ knorms,
    const u16* __restrict__ vrows, int N, const float* __restrict__ W2,
    float* __restrict__ st, unsigned* tick, unsigned nblocks) {
    att_loop(krows, knorms, vrows, st, N);
    if (last_block_ticket(tick, nblocks)) {
        __threadfence();
        finish_hop_body(W2, st);
    }
}

// ===========================================================================
// K5: candidate gather + cosine, fused (enc_cands never materialized).
// ===========================================================================
__global__ void k5_final(const float* __restrict__ cemb,
                         const int* __restrict__ cands, int NC,
                         const float* __restrict__ st, float* __restrict__ out) {
    const int lane = threadIdx.x & 63;
    const int half = lane >> 5;
    const int hl = lane & 31;
    const int gw = (int)((blockIdx.x * blockDim.x + threadIdx.x) >> 6);
    const int nw = (int)((gridDim.x * blockDim.x) >> 6);
    const float4 q4 = *(const float4*)(st + 4 * hl);
    const float qn = st[384];
    const int npair = (NC + 1) >> 1;
    for (int p = gw; p < npair; p += nw) {
        const int row = 2 * p + half;
        const bool valid = row < NC;
        const int rowc = valid ? row : (NC - 1);
        int myid = 0;
        if (hl < 20) myid = cands[(long)rowc * 20 + hl];
        float4 acc = {0.f, 0.f, 0.f, 0.f};
#pragma unroll
        for (int t = 0; t < 20; ++t) {
            const int idx = __shfl(myid, (half << 5) + t, 64);
            const float4 e = *(const float4*)(cemb + (long)idx * D + 4 * hl);
            acc.x += e.x; acc.y += e.y; acc.z += e.z; acc.w += e.w;
        }
        float dot = halfwave_sum(acc.x * q4.x + acc.y * q4.y +
                                 acc.z * q4.z + acc.w * q4.w);
        float nsq = halfwave_sum(acc.x * acc.x + acc.y * acc.y +
                                 acc.z * acc.z + acc.w * acc.w);
        if (valid && hl == 0) out[row] = dot / fmaxf(sqrtf(nsq) * qn, EPS);
    }
}

// ===========================================================================
// Fallback path (workspace too small): fp32 on-the-fly gather, multi-kernel.
// ===========================================================================
__global__ void encode_small(const float* __restrict__ emb,
                             const int* __restrict__ pers, int NP, int LP,
                             const int* __restrict__ xs, int LQ,
                             float* __restrict__ pers_rows,
                             float* __restrict__ pnorms,
                             float* __restrict__ st) {
    int lane = threadIdx.x & 63;
    int w = threadIdx.x >> 6;
    for (int i = w; i <= NP; i += 4) {
        const int* ids;
        int L;
        float* out;
        float* nrm;
        if (i < NP) { ids = pers + (long)i * LP; L = LP; out = pers_rows + (long)i * D; nrm = pnorms + i; }
        else        { ids = xs; L = LQ; out = st; nrm = st + 384; }
        float2 acc = {0.f, 0.f};
        for (int t = 0; t < L; ++t) {
            int idx = ids[t];
            const float2 e = *(const float2*)(emb + (long)idx * D + 2 * lane);
            acc.x += e.x;
            acc.y += e.y;
        }
        *(float2*)(out + 2 * lane) = acc;
        float sq = wave_sum(acc.x * acc.x + acc.y * acc.y);
        if (lane == 0) *nrm = sqrtf(sq);
    }
}

__global__ void persona_hop_k(const float* __restrict__ pers_rows,
                              const float* __restrict__ pnorms,
                              const float* __restrict__ W,
                              float* __restrict__ st, int NP) {
    persona_hop_body(pers_rows, pnorms, W, st, NP);
}

__global__ void big_att_rc(const float* __restrict__ emb,
                           const int* __restrict__ kids,
                           const int* __restrict__ vids,
                           float* __restrict__ st, int N) {
    const int tid = threadIdx.x;
    const int lane = tid & 63;
    const int half = lane >> 5;
    const int hl = lane & 31;
    const int gw = (int)((blockIdx.x * blockDim.x + tid) >> 6);
    const int nw = (int)((gridDim.x * blockDim.x) >> 6);
    const float4 qp = *(const float4*)(st + 128 + 4 * hl);
    const float qpn = st[385];
    float4 hacc = {0.f, 0.f, 0.f, 0.f};
    float esum = 0.f;
    const int npair = (N + 1) >> 1;
    for (int p = gw; p < npair; p += nw) {
        const int row = 2 * p + half;
        const bool valid = row < N;
        const int rowc = valid ? row : (N - 1);
        int kid = 0, vid = 0;
        if (hl < 20) {
            kid = kids[(long)rowc * 20 + hl];
            vid = vids[(long)rowc * 20 + hl];
        }
        float4 ka = {0.f, 0.f, 0.f, 0.f}, va = {0.f, 0.f, 0.f, 0.f};
#pragma unroll
        for (int t = 0; t < 20; ++t) {
            const int ki = __shfl(kid, (half << 5) + t, 64);
            const int vi = __shfl(vid, (half << 5) + t, 64);
            const float4 ke = *(const float4*)(emb + (long)ki * D + 4 * hl);
            const float4 ve = *(const float4*)(emb + (long)vi * D + 4 * hl);
            ka.x += ke.x; ka.y += ke.y; ka.z += ke.z; ka.w += ke.w;
            va.x += ve.x; va.y += ve.y; va.z += ve.z; va.w += ve.w;
        }
        float nsq = halfwave_sum(ka.x * ka.x + ka.y * ka.y + ka.z * ka.z + ka.w * ka.w);
        float dot = halfwave_sum(ka.x * qp.x + ka.y * qp.y + ka.z * qp.z + ka.w * qp.w);
        const float c = dot / fmaxf(sqrtf(nsq) * qpn, EPS);
        float e = __expf(c);
        if (!valid) e = 0.f;
        hacc.x += e * va.x; hacc.y += e * va.y;
        hacc.z += e * va.z; hacc.w += e * va.w;
        if (hl == 0) esum += e;
    }
    att_block_reduce(hacc, esum, st);
}

__global__ void mid_hop_k(const float* __restrict__ W1, const float* __restrict__ W2,
                          const float* __restrict__ pers_rows,
                          const float* __restrict__ pnorms,
                          float* __restrict__ st, int NP) {
    mid_hop_body(W1, W2, pers_rows, pnorms, st, NP);
}

__global__ void finish_hop_k(const float* __restrict__ W, float* __restrict__ st) {
    finish_hop_body(W, st);
}

static inline size_t align16(size_t b) { return (b + 15) & ~(size_t)15; }

extern "C" void kernel_launch(void* const* d_in, const int* in_sizes, int n_in,
                              void* d_out, int out_size, void* d_ws, size_t ws_size,
                              hipStream_t stream) {
    const int* xs = (const int*)d_in[0];
    const int* cands = (const int*)d_in[1];
    const int* pers = (const int*)d_in[2];
    const int* keys = (const int*)d_in[3];
    const int* values = (const int*)d_in[4];
    const float* semb = (const float*)d_in[6];
    const float* cemb = (const float*)d_in[7];
    const float* RW = (const float*)d_in[8];
    const float* R2W = (const float*)d_in[9];
    float* out = (float*)d_out;

    const int L = 20;
    const int LQ = in_sizes[0];
    const int VD = in_sizes[6];         // V*D
    const int NMEM = in_sizes[3] / L;   // 65536
    const int NCAND = in_sizes[1] / L;  // 10000
    const int NPERS = in_sizes[2] / L;  // 20

    size_t need = align16((size_t)VD * 2) + 2 * align16((size_t)NMEM * D * 2) +
                  align16((size_t)NMEM * 4) + align16((size_t)NPERS * D * 4) +
                  align16((size_t)NPERS * 4) + 512 * 4;
    bool stored = (d_ws != nullptr) && (ws_size >= need) && (NMEM % 2 == 0) &&
                  ((VD & 3) == 0);

    const int THR = 256;

    if (stored) {
        char* base = (char*)d_ws;
        u16* tbl16 = (u16*)base;  base += align16((size_t)VD * 2);
        u16* kb = (u16*)base;     base += align16((size_t)NMEM * D * 2);
        u16* vb = (u16*)base;     base += align16((size_t)NMEM * D * 2);
        float* knorms = (float*)base;   base += align16((size_t)NMEM * 4);
        float* enc_pers = (float*)base; base += align16((size_t)NPERS * D * 4);
        float* pnorms = (float*)base;   base += align16((size_t)NPERS * 4);
        float* st = (float*)base;
        unsigned* ticks = (unsigned*)(st + 448);

        hipMemsetAsync((void*)ticks, 0, 16, stream);

        // K1: table convert + (winner) persona/q encode + persona hop 1
        const unsigned G1 = 1024;
        k1_prep<<<G1, THR, 0, stream>>>(semb, VD / 4, tbl16, pers, NPERS, xs, LQ,
                                        RW, enc_pers, pnorms, st, &ticks[0], G1);
        // K2: pure kv gather, full oversubscription (1 pair/wave)
        {
            int npair = NMEM / 2;
            int blocks = (npair + 3) / 4;  // 4 waves/block
            encode_kv_bf16<20><<<blocks, THR, 0, stream>>>(tbl16, keys, values,
                                                           NMEM, kb, vb, knorms);
        }
        // K3: attention hop 1 + (winner) mid-hop
        const unsigned G3 = 1024;
        k3_att1<<<G3, THR, 0, stream>>>(kb, knorms, vb, NMEM, RW, R2W, enc_pers,
                                        pnorms, NPERS, st, &ticks[1], G3);
        // K4: attention hop 2 + (winner) finish-hop
        const unsigned G4 = 1024;
        k4_att2<<<G4, THR, 0, stream>>>(kb, knorms, vb, NMEM, R2W, st,
                                        &ticks[2], G4);
        // K5: candidate gather + cosine
        int nblk5 = (((NCAND + 1) / 2) + 3) / 4;
        k5_final<<<nblk5, THR, 0, stream>>>(cemb, cands, NCAND, st, out);
        (void)n_in; (void)out_size;
        return;
    }

    // -------- fallback: fp32 on-the-fly gather, multi-kernel --------
    char* base = (char*)d_ws;
    float* enc_pers = (float*)base; base += align16((size_t)NPERS * D * 4);
    float* pnorms = (float*)base;   base += align16((size_t)NPERS * 4);
    float* st = (float*)base;

    encode_small<<<1, THR, 0, stream>>>(semb, pers, NPERS, L, xs, LQ,
                                        enc_pers, pnorms, st);
    persona_hop_k<<<1, THR, 0, stream>>>(enc_pers, pnorms, RW, st, NPERS);
    big_att_rc<<<1024, THR, 0, stream>>>(semb, keys, values, st, NMEM);
    mid_hop_k<<<1, THR, 0, stream>>>(RW, R2W, enc_pers, pnorms, st, NPERS);
    big_att_rc<<<1024, THR, 0, stream>>>(semb, keys, values, st, NMEM);
    finish_hop_k<<<1, THR, 0, stream>>>(R2W, st);
    int nblk5 = (((NCAND + 1) / 2) + 3) / 4;
    k5_final<<<nblk5, THR, 0, stream>>>(cemb, cands, NCAND, st, out);

    (void)n_in; (void)out_size;
}

// Round 7
// 352.104 us; speedup vs baseline: 2.3995x; 1.1642x over previous
//
#include <hip/hip_runtime.h>
#include <math.h>
#include <stdint.h>

#define D 128
#define EPS 1e-6f
typedef unsigned short u16;

// ---------------------------------------------------------------------------
// state layout (floats), 16B-aligned base:
//   st[0..127]   : q
//   st[128..255] : q_plus
//   st[256..383] : hop accumulator (device atomicAdd targets)
//   st[384]      : ||q||   st[385] : ||q_plus||   st[386] : sum-of-exp
// NO device-scope fences anywhere: cross-kernel visibility comes from stream
// ordering (measured r6: any __threadfence after bulk writes costs ~100 us
// of serialized L2 writeback on MI355X).
// ---------------------------------------------------------------------------

__device__ __forceinline__ float wave_sum(float v) {
#pragma unroll
    for (int off = 32; off > 0; off >>= 1) v += __shfl_xor(v, off, 64);
    return v;
}
__device__ __forceinline__ float halfwave_sum(float v) {
#pragma unroll
    for (int off = 16; off > 0; off >>= 1) v += __shfl_xor(v, off, 32);
    return v;
}

__device__ __forceinline__ float bf2f(u16 h) {
    union { unsigned u; float f; } x;
    x.u = ((unsigned)h) << 16;
    return x.f;
}
__device__ __forceinline__ u16 f2bf(float f) {  // round-to-nearest-even
    union { float f; unsigned u; } x;
    x.f = f;
    unsigned u = x.u;
    return (u16)((u + 0x7fff + ((u >> 16) & 1)) >> 16);
}

// ===========================================================================
// K1: streaming fp32 -> bf16 table conversion. Plain kernel, full grid.
// ===========================================================================
__global__ void table_to_bf16(const float4* __restrict__ src,
                              ushort4* __restrict__ dst, int n4) {
    int i = blockIdx.x * blockDim.x + threadIdx.x;
    if (i < n4) {
        float4 v = src[i];
        ushort4 o;
        o.x = f2bf(v.x); o.y = f2bf(v.y); o.z = f2bf(v.z); o.w = f2bf(v.w);
        dst[i] = o;
    }
}

// ===========================================================================
// K2: fused key+value gather from bf16 table. 2 rows/wave (half-wave each,
// ushort4 = 8B/lane), 1 pair per wave via full grid (max occupancy; measured
// r3: 73 us, 46% occ — batching pairs into fewer blocks regressed, r5).
// ===========================================================================
template <int L>
__global__ void encode_kv_bf16(const u16* __restrict__ tbl,
                               const int* __restrict__ kids,
                               const int* __restrict__ vids, int N,
                               u16* __restrict__ krows, u16* __restrict__ vrows,
                               float* __restrict__ knorms) {
    const int lane = threadIdx.x & 63;
    const int half = lane >> 5;
    const int hl = lane & 31;
    int gw = (int)((blockIdx.x * blockDim.x + threadIdx.x) >> 6);
    int nw = (int)((gridDim.x * blockDim.x) >> 6);
    const int npair = (N + 1) >> 1;
    for (int p = gw; p < npair; p += nw) {
        const int row = 2 * p + half;
        const bool valid = row < N;
        const int rowc = valid ? row : (N - 1);
        int kid = 0, vid = 0;
        if (hl < L) {
            kid = kids[(long)rowc * L + hl];
            vid = vids[(long)rowc * L + hl];
        }
        float4 ka = {0.f, 0.f, 0.f, 0.f}, va = {0.f, 0.f, 0.f, 0.f};
#pragma unroll
        for (int t = 0; t < L; ++t) {
            const int ki = __shfl(kid, (half << 5) + t, 64);
            const int vi = __shfl(vid, (half << 5) + t, 64);
            const ushort4 ke = *(const ushort4*)(tbl + (long)ki * D + 4 * hl);
            const ushort4 ve = *(const ushort4*)(tbl + (long)vi * D + 4 * hl);
            ka.x += bf2f(ke.x); ka.y += bf2f(ke.y);
            ka.z += bf2f(ke.z); ka.w += bf2f(ke.w);
            va.x += bf2f(ve.x); va.y += bf2f(ve.y);
            va.z += bf2f(ve.z); va.w += bf2f(ve.w);
        }
        if (valid) {
            ushort4 ko, vo;
            ko.x = f2bf(ka.x); ko.y = f2bf(ka.y); ko.z = f2bf(ka.z); ko.w = f2bf(ka.w);
            vo.x = f2bf(va.x); vo.y = f2bf(va.y); vo.z = f2bf(va.z); vo.w = f2bf(va.w);
            *(ushort4*)(krows + (long)row * D + 4 * hl) = ko;
            *(ushort4*)(vrows + (long)row * D + 4 * hl) = vo;
        }
        float sq = ka.x * ka.x + ka.y * ka.y + ka.z * ka.z + ka.w * ka.w;
        sq = halfwave_sum(sq);
        if (valid && hl == 0) knorms[row] = sqrtf(sq);
    }
}

// ===========================================================================
// Small fp32 encodes: persona rows + q, one block.
// ===========================================================================
__global__ void encode_small(const float* __restrict__ emb,
                             const int* __restrict__ pers, int NP, int LP,
                             const int* __restrict__ xs, int LQ,
                             float* __restrict__ pers_rows,
                             float* __restrict__ pnorms,
                             float* __restrict__ st) {
    int lane = threadIdx.x & 63;
    int w = threadIdx.x >> 6;
    for (int i = w; i <= NP; i += 4) {
        const int* ids;
        int L;
        float* out;
        float* nrm;
        if (i < NP) { ids = pers + (long)i * LP; L = LP; out = pers_rows + (long)i * D; nrm = pnorms + i; }
        else        { ids = xs; L = LQ; out = st; nrm = st + 384; }
        float2 acc = {0.f, 0.f};
        for (int t = 0; t < L; ++t) {
            int idx = ids[t];
            const float2 e = *(const float2*)(emb + (long)idx * D + 2 * lane);
            acc.x += e.x;
            acc.y += e.y;
        }
        *(float2*)(out + 2 * lane) = acc;
        float sq = wave_sum(acc.x * acc.x + acc.y * acc.y);
        if (lane == 0) *nrm = sqrtf(sq);
    }
}

// ===========================================================================
// Hop kernels (1 block, 128 threads) — round-3 known-good versions.
// ===========================================================================
__global__ void persona_hop(const float* __restrict__ pers_rows,
                            const float* __restrict__ pnorms,
                            const float* __restrict__ W,
                            float* __restrict__ st, int NP) {
    __shared__ float qsh[D];
    __shared__ float att[64];
    __shared__ float qh[D];
    __shared__ float red[2];
    int tid = threadIdx.x;
    qsh[tid] = st[tid];
    __syncthreads();
    if (tid < NP) {
        float dot = 0.f;
        for (int d2 = 0; d2 < D; ++d2) dot += pers_rows[tid * D + d2] * qsh[d2];
        att[tid] = dot / fmaxf(pnorms[tid] * st[384], EPS);
    }
    __syncthreads();
    if (tid == 0) {
        float m = -1e30f;
        for (int p = 0; p < NP; ++p) m = fmaxf(m, att[p]);
        float s = 0.f;
        for (int p = 0; p < NP; ++p) { att[p] = __expf(att[p] - m); s += att[p]; }
        float inv = 1.f / s;
        for (int p = 0; p < NP; ++p) att[p] *= inv;
    }
    __syncthreads();
    float h = 0.f;
    for (int p = 0; p < NP; ++p) h += att[p] * pers_rows[p * D + tid];
    qh[tid] = qsh[tid] + h;
    __syncthreads();
    float qp = 0.f;
    for (int d2 = 0; d2 < D; ++d2) qp += W[tid * D + d2] * qh[d2];
    st[128 + tid] = qp;
    float sq = wave_sum(qp * qp);
    if ((tid & 63) == 0) red[tid >> 6] = sq;
    __syncthreads();
    if (tid == 0) st[385] = sqrtf(red[0] + red[1]);
    st[256 + tid] = 0.f;  // zero accumulators for upcoming attention
    if (tid == 0) st[386] = 0.f;
}

__global__ void mid_hop(const float* __restrict__ W1, const float* __restrict__ W2,
                        const float* __restrict__ pers_rows,
                        const float* __restrict__ pnorms,
                        float* __restrict__ st, int NP) {
    __shared__ float qh[D];
    __shared__ float qsh[D];
    __shared__ float att[64];
    __shared__ float red[2];
    int tid = threadIdx.x;
    float inv = 1.f / st[386];
    qh[tid] = st[128 + tid] + st[256 + tid] * inv;
    __syncthreads();
    float qn = 0.f;
    for (int d2 = 0; d2 < D; ++d2) qn += W1[tid * D + d2] * qh[d2];
    qsh[tid] = qn;
    st[tid] = qn;
    float sq = wave_sum(qn * qn);
    if ((tid & 63) == 0) red[tid >> 6] = sq;
    __syncthreads();
    float qnorm = sqrtf(red[0] + red[1]);
    if (tid == 0) st[384] = qnorm;
    if (tid < NP) {
        float dot = 0.f;
        for (int d2 = 0; d2 < D; ++d2) dot += pers_rows[tid * D + d2] * qsh[d2];
        att[tid] = dot / fmaxf(pnorms[tid] * qnorm, EPS);
    }
    __syncthreads();
    if (tid == 0) {
        float m = -1e30f;
        for (int p = 0; p < NP; ++p) m = fmaxf(m, att[p]);
        float s = 0.f;
        for (int p = 0; p < NP; ++p) { att[p] = __expf(att[p] - m); s += att[p]; }
        float is = 1.f / s;
        for (int p = 0; p < NP; ++p) att[p] *= is;
    }
    __syncthreads();
    float h = 0.f;
    for (int p = 0; p < NP; ++p) h += att[p] * pers_rows[p * D + tid];
    qh[tid] = qsh[tid] + h;
    __syncthreads();
    float qp = 0.f;
    for (int d2 = 0; d2 < D; ++d2) qp += W2[tid * D + d2] * qh[d2];
    st[128 + tid] = qp;
    float sq2 = wave_sum(qp * qp);
    if ((tid & 63) == 0) red[tid >> 6] = sq2;
    __syncthreads();
    if (tid == 0) st[385] = sqrtf(red[0] + red[1]);
    st[256 + tid] = 0.f;
    if (tid == 0) st[386] = 0.f;
}

__global__ void finish_hop(const float* __restrict__ W, float* __restrict__ st) {
    __shared__ float qh[D];
    __shared__ float red[2];
    int tid = threadIdx.x;
    float inv = 1.f / st[386];
    qh[tid] = st[128 + tid] + st[256 + tid] * inv;
    __syncthreads();
    float qn = 0.f;
    for (int d2 = 0; d2 < D; ++d2) qn += W[tid * D + d2] * qh[d2];
    st[tid] = qn;
    float sq = wave_sum(qn * qn);
    if ((tid & 63) == 0) red[tid >> 6] = sq;
    __syncthreads();
    if (tid == 0) st[384] = sqrtf(red[0] + red[1]);
}

// ===========================================================================
// Big attention over stored bf16 rows (1024 blocks). r3 known-good.
// ===========================================================================
__global__ void big_att_bf16(const u16* __restrict__ krows,
                             const float* __restrict__ knorms,
                             const u16* __restrict__ vrows,
                             float* __restrict__ st, int N) {
    __shared__ float s[129];
    int tid = threadIdx.x;
    int lane = tid & 63;
    int half = lane >> 5, hl = lane & 31;
    int gw = (int)((blockIdx.x * blockDim.x + tid) >> 6);
    int nw = (int)((gridDim.x * blockDim.x) >> 6);
    const float4 qp = *(const float4*)(st + 128 + 4 * hl);
    const float qpn = st[385];
    float4 acc = {0.f, 0.f, 0.f, 0.f};
    float esum = 0.f;
    const int npair = N >> 1;
    for (int p = gw; p < npair; p += nw) {
        const int i = 2 * p + half;
        const ushort4 kh = *(const ushort4*)(krows + (long)i * D + 4 * hl);
        float dot = bf2f(kh.x) * qp.x + bf2f(kh.y) * qp.y +
                    bf2f(kh.z) * qp.z + bf2f(kh.w) * qp.w;
        dot = halfwave_sum(dot);
        const float c = dot / fmaxf(knorms[i] * qpn, EPS);
        const float e = __expf(c);
        const ushort4 vh = *(const ushort4*)(vrows + (long)i * D + 4 * hl);
        acc.x += e * bf2f(vh.x);
        acc.y += e * bf2f(vh.y);
        acc.z += e * bf2f(vh.z);
        acc.w += e * bf2f(vh.w);
        if (hl == 0) esum += e;
    }
    acc.x += __shfl_xor(acc.x, 32, 64);
    acc.y += __shfl_xor(acc.y, 32, 64);
    acc.z += __shfl_xor(acc.z, 32, 64);
    acc.w += __shfl_xor(acc.w, 32, 64);
    esum += __shfl_xor(esum, 32, 64);
    if (tid < 129) s[tid] = 0.f;
    __syncthreads();
    if (half == 0) {
        atomicAdd(&s[4 * hl + 0], acc.x);
        atomicAdd(&s[4 * hl + 1], acc.y);
        atomicAdd(&s[4 * hl + 2], acc.z);
        atomicAdd(&s[4 * hl + 3], acc.w);
        if (hl == 0) atomicAdd(&s[128], esum);
    }
    __syncthreads();
    if (tid < 128) atomicAdd(&st[256 + tid], s[tid]);
    if (tid == 128) atomicAdd(&st[386], s[128]);
}

// ===========================================================================
// K5: candidate gather + cosine, fused (enc_cands never materialized).
// ===========================================================================
__global__ void k5_final(const float* __restrict__ cemb,
                         const int* __restrict__ cands, int NC,
                         const float* __restrict__ st, float* __restrict__ out) {
    const int lane = threadIdx.x & 63;
    const int half = lane >> 5;
    const int hl = lane & 31;
    const int gw = (int)((blockIdx.x * blockDim.x + threadIdx.x) >> 6);
    const int nw = (int)((gridDim.x * blockDim.x) >> 6);
    const float4 q4 = *(const float4*)(st + 4 * hl);
    const float qn = st[384];
    const int npair = (NC + 1) >> 1;
    for (int p = gw; p < npair; p += nw) {
        const int row = 2 * p + half;
        const bool valid = row < NC;
        const int rowc = valid ? row : (NC - 1);
        int myid = 0;
        if (hl < 20) myid = cands[(long)rowc * 20 + hl];
        float4 acc = {0.f, 0.f, 0.f, 0.f};
#pragma unroll
        for (int t = 0; t < 20; ++t) {
            const int idx = __shfl(myid, (half << 5) + t, 64);
            const float4 e = *(const float4*)(cemb + (long)idx * D + 4 * hl);
            acc.x += e.x; acc.y += e.y; acc.z += e.z; acc.w += e.w;
        }
        float dot = halfwave_sum(acc.x * q4.x + acc.y * q4.y +
                                 acc.z * q4.z + acc.w * q4.w);
        float nsq = halfwave_sum(acc.x * acc.x + acc.y * acc.y +
                                 acc.z * acc.z + acc.w * acc.w);
        if (valid && hl == 0) out[row] = dot / fmaxf(sqrtf(nsq) * qn, EPS);
    }
}

// ===========================================================================
// Fallback big attention: fp32 on-the-fly gather (workspace too small).
// ===========================================================================
__global__ void big_att_rc(const float* __restrict__ emb,
                           const int* __restrict__ kids,
                           const int* __restrict__ vids,
                           float* __restrict__ st, int N) {
    __shared__ float s[129];
    const int tid = threadIdx.x;
    const int lane = tid & 63;
    const int half = lane >> 5;
    const int hl = lane & 31;
    const int gw = (int)((blockIdx.x * blockDim.x + tid) >> 6);
    const int nw = (int)((gridDim.x * blockDim.x) >> 6);
    const float4 qp = *(const float4*)(st + 128 + 4 * hl);
    const float qpn = st[385];
    float4 hacc = {0.f, 0.f, 0.f, 0.f};
    float esum = 0.f;
    const int npair = (N + 1) >> 1;
    for (int p = gw; p < npair; p += nw) {
        const int row = 2 * p + half;
        const bool valid = row < N;
        const int rowc = valid ? row : (N - 1);
        int kid = 0, vid = 0;
        if (hl < 20) {
            kid = kids[(long)rowc * 20 + hl];
            vid = vids[(long)rowc * 20 + hl];
        }
        float4 ka = {0.f, 0.f, 0.f, 0.f}, va = {0.f, 0.f, 0.f, 0.f};
#pragma unroll
        for (int t = 0; t < 20; ++t) {
            const int ki = __shfl(kid, (half << 5) + t, 64);
            const int vi = __shfl(vid, (half << 5) + t, 64);
            const float4 ke = *(const float4*)(emb + (long)ki * D + 4 * hl);
            const float4 ve = *(const float4*)(emb + (long)vi * D + 4 * hl);
            ka.x += ke.x; ka.y += ke.y; ka.z += ke.z; ka.w += ke.w;
            va.x += ve.x; va.y += ve.y; va.z += ve.z; va.w += ve.w;
        }
        float nsq = halfwave_sum(ka.x * ka.x + ka.y * ka.y + ka.z * ka.z + ka.w * ka.w);
        float dot = halfwave_sum(ka.x * qp.x + ka.y * qp.y + ka.z * qp.z + ka.w * qp.w);
        const float c = dot / fmaxf(sqrtf(nsq) * qpn, EPS);
        float e = __expf(c);
        if (!valid) e = 0.f;
        hacc.x += e * va.x; hacc.y += e * va.y;
        hacc.z += e * va.z; hacc.w += e * va.w;
        if (hl == 0) esum += e;
    }
    hacc.x += __shfl_xor(hacc.x, 32, 64);
    hacc.y += __shfl_xor(hacc.y, 32, 64);
    hacc.z += __shfl_xor(hacc.z, 32, 64);
    hacc.w += __shfl_xor(hacc.w, 32, 64);
    esum += __shfl_xor(esum, 32, 64);
    if (tid < 129) s[tid] = 0.f;
    __syncthreads();
    if (half == 0) {
        atomicAdd(&s[4 * hl + 0], hacc.x);
        atomicAdd(&s[4 * hl + 1], hacc.y);
        atomicAdd(&s[4 * hl + 2], hacc.z);
        atomicAdd(&s[4 * hl + 3], hacc.w);
        if (hl == 0) atomicAdd(&s[128], esum);
    }
    __syncthreads();
    if (tid < 128) atomicAdd(&st[256 + tid], s[tid]);
    if (tid == 128) atomicAdd(&st[386], s[128]);
}

static inline size_t align16(size_t b) { return (b + 15) & ~(size_t)15; }

extern "C" void kernel_launch(void* const* d_in, const int* in_sizes, int n_in,
                              void* d_out, int out_size, void* d_ws, size_t ws_size,
                              hipStream_t stream) {
    const int* xs = (const int*)d_in[0];
    const int* cands = (const int*)d_in[1];
    const int* pers = (const int*)d_in[2];
    const int* keys = (const int*)d_in[3];
    const int* values = (const int*)d_in[4];
    const float* semb = (const float*)d_in[6];
    const float* cemb = (const float*)d_in[7];
    const float* RW = (const float*)d_in[8];
    const float* R2W = (const float*)d_in[9];
    float* out = (float*)d_out;

    const int L = 20;
    const int LQ = in_sizes[0];
    const int VD = in_sizes[6];         // V*D
    const int NMEM = in_sizes[3] / L;   // 65536
    const int NCAND = in_sizes[1] / L;  // 10000
    const int NPERS = in_sizes[2] / L;  // 20

    size_t need = align16((size_t)VD * 2) + 2 * align16((size_t)NMEM * D * 2) +
                  align16((size_t)NMEM * 4) + align16((size_t)NPERS * D * 4) +
                  align16((size_t)NPERS * 4) + 512 * 4;
    bool stored = (d_ws != nullptr) && (ws_size >= need) && (NMEM % 2 == 0) &&
                  ((VD & 3) == 0);

    const int THR = 256;
    char* base = (char*)d_ws;
    u16 *tbl16 = nullptr, *kb = nullptr, *vb = nullptr;
    float* knorms = nullptr;
    if (stored) {
        tbl16 = (u16*)base;  base += align16((size_t)VD * 2);
        kb = (u16*)base;     base += align16((size_t)NMEM * D * 2);
        vb = (u16*)base;     base += align16((size_t)NMEM * D * 2);
        knorms = (float*)base; base += align16((size_t)NMEM * 4);
    }
    float* enc_pers = (float*)base; base += align16((size_t)NPERS * D * 4);
    float* pnorms = (float*)base;   base += align16((size_t)NPERS * 4);
    float* st = (float*)base;

    if (stored) {
        // K1: plain table convert, full grid (no fences/tickets)
        int n4 = VD / 4;
        table_to_bf16<<<(n4 + THR - 1) / THR, THR, 0, stream>>>(
            (const float4*)semb, (ushort4*)tbl16, n4);
        // K2: fused kv gather at full oversubscription (1 pair/wave)
        {
            int npair = NMEM / 2;
            int blocks = (npair + 3) / 4;  // 4 waves/block
            encode_kv_bf16<20><<<blocks, THR, 0, stream>>>(tbl16, keys, values,
                                                           NMEM, kb, vb, knorms);
        }
        // small encodes + hop 1 front-end
        encode_small<<<1, THR, 0, stream>>>(semb, pers, NPERS, L, xs, LQ,
                                            enc_pers, pnorms, st);
        persona_hop<<<1, 128, 0, stream>>>(enc_pers, pnorms, RW, st, NPERS);
        // attention hop 1
        big_att_bf16<<<1024, THR, 0, stream>>>(kb, knorms, vb, st, NMEM);
        mid_hop<<<1, 128, 0, stream>>>(RW, R2W, enc_pers, pnorms, st, NPERS);
        // attention hop 2
        big_att_bf16<<<1024, THR, 0, stream>>>(kb, knorms, vb, st, NMEM);
        finish_hop<<<1, 128, 0, stream>>>(R2W, st);
        // final: fused candidate gather + cosine
        int nblk5 = (((NCAND + 1) / 2) + 3) / 4;
        k5_final<<<nblk5, THR, 0, stream>>>(cemb, cands, NCAND, st, out);
        (void)n_in; (void)out_size;
        return;
    }

    // -------- fallback: fp32 on-the-fly gather --------
    encode_small<<<1, THR, 0, stream>>>(semb, pers, NPERS, L, xs, LQ,
                                        enc_pers, pnorms, st);
    persona_hop<<<1, 128, 0, stream>>>(enc_pers, pnorms, RW, st, NPERS);
    big_att_rc<<<1024, THR, 0, stream>>>(semb, keys, values, st, NMEM);
    mid_hop<<<1, 128, 0, stream>>>(RW, R2W, enc_pers, pnorms, st, NPERS);
    big_att_rc<<<1024, THR, 0, stream>>>(semb, keys, values, st, NMEM);
    finish_hop<<<1, 128, 0, stream>>>(R2W, st);
    int nblk5 = (((NCAND + 1) / 2) + 3) / 4;
    k5_final<<<nblk5, THR, 0, stream>>>(cemb, cands, NCAND, st, out);

    (void)n_in; (void)out_size;
}